// Round 1
// baseline (2718.676 us; speedup 1.0000x reference)
//
#include <hip/hip_runtime.h>

#define N_NODES 50000
#define N_FEAT  128
#define HID     64
#define N_EDGES 1600000
#define LN_EPS  1e-5f

__device__ __forceinline__ float bcastf(float v, int l){
  return __uint_as_float(__builtin_amdgcn_readlane(__float_as_uint(v), l));
}

// ---------------- setup: degree count ----------------
__global__ void count_kernel(const int* __restrict__ ep, const int* __restrict__ en,
                             int* __restrict__ cnt_p, int* __restrict__ cnt_n){
  int t = blockIdx.x * blockDim.x + threadIdx.x;
  if (t < N_EDGES){
    atomicAdd(&cnt_p[ep[N_EDGES + t]], 1);
  } else if (t < 2 * N_EDGES){
    int e = t - N_EDGES;
    atomicAdd(&cnt_n[en[N_EDGES + e]], 1);
  }
}

// ---------------- setup: exclusive scan (single block, both arrays) ----------------
__global__ void scan2_kernel(const int* __restrict__ c0, int* __restrict__ o0,
                             const int* __restrict__ c1, int* __restrict__ o1){
  __shared__ int wsum[16];
  __shared__ int wexcl[16];
  __shared__ int carry_s;
  const int tid = threadIdx.x;          // 1024 threads
  const int lane = tid & 63, wid = tid >> 6;
  for (int a = 0; a < 2; ++a){
    const int* c = a ? c1 : c0;
    int* o = a ? o1 : o0;
    if (tid == 0) carry_s = 0;
    __syncthreads();
    for (int base = 0; base < N_NODES; base += 1024){
      int idx = base + tid;
      int v = (idx < N_NODES) ? c[idx] : 0;
      int x = v;
      #pragma unroll
      for (int d = 1; d < 64; d <<= 1){
        int y = __shfl_up(x, d);
        if (lane >= d) x += y;
      }
      if (lane == 63) wsum[wid] = x;
      __syncthreads();
      int block_total = 0;
      if (tid == 0){
        int s = 0;
        for (int wv = 0; wv < 16; ++wv){ wexcl[wv] = s; s += wsum[wv]; }
        block_total = s;
      }
      __syncthreads();
      if (idx < N_NODES) o[idx] = carry_s + wexcl[wid] + (x - v);
      __syncthreads();
      if (tid == 0) carry_s += block_total;
      __syncthreads();
    }
    if (tid == 0) o[N_NODES] = carry_s;
    __syncthreads();
  }
}

// ---------------- setup: dinv = rsqrt(indeg + 1) ----------------
__global__ void dinv_kernel(const int* __restrict__ cnt_p, const int* __restrict__ cnt_n,
                            float* __restrict__ dp, float* __restrict__ dn){
  int i = blockIdx.x * blockDim.x + threadIdx.x;
  if (i < N_NODES){
    dp[i] = rsqrtf((float)(cnt_p[i] + 1));
    dn[i] = rsqrtf((float)(cnt_n[i] + 1));
  }
}

// ---------------- setup: CSR fill ----------------
__global__ void fill_kernel(const int* __restrict__ ep, const int* __restrict__ en,
                            const int* __restrict__ off_p, const int* __restrict__ off_n,
                            int* __restrict__ cur_p, int* __restrict__ cur_n,
                            const float* __restrict__ dinv_p, const float* __restrict__ dinv_n,
                            int* __restrict__ cs_p, float* __restrict__ cw_p,
                            int* __restrict__ cs_n, float* __restrict__ cw_n){
  int t = blockIdx.x * blockDim.x + threadIdx.x;
  if (t < N_EDGES){
    int s = ep[t], d = ep[N_EDGES + t];
    int p = atomicAdd(&cur_p[d], 1);
    int ix = off_p[d] + p;
    cs_p[ix] = s; cw_p[ix] = dinv_p[s];
  } else if (t < 2 * N_EDGES){
    int e = t - N_EDGES;
    int s = en[e], d = en[N_EDGES + e];
    int p = atomicAdd(&cur_n[d], 1);
    int ix = off_n[d] + p;
    cs_n[ix] = s; cw_n[ix] = dinv_n[s];
  }
}

// ---------------- encoder: h0 = x @ W_enc^T + b_enc ----------------
__global__ __launch_bounds__(256) void encoder_kernel(
    const float* __restrict__ x, const float* __restrict__ Wenc, const float* __restrict__ benc,
    float* __restrict__ hbase, float* __restrict__ hin){
  __shared__ float wt[N_FEAT * HID];           // wt[k*64+j] = W[j*128+k]
  for (int i = threadIdx.x; i < N_FEAT * HID; i += 256){
    int j = i >> 7, k = i & 127;
    wt[k * HID + j] = Wenc[i];
  }
  __syncthreads();
  int lane = threadIdx.x & 63, wid = threadIdx.x >> 6;
  int gw = blockIdx.x * 4 + wid, nw = gridDim.x * 4;
  for (int node = gw; node < N_NODES; node += nw){
    float xa = x[node * N_FEAT + lane];
    float xb = x[node * N_FEAT + 64 + lane];
    float acc = benc[lane];
    #pragma unroll
    for (int k = 0; k < 64; ++k){
      acc += bcastf(xa, k) * wt[k * HID + lane];
      acc += bcastf(xb, k) * wt[(64 + k) * HID + lane];
    }
    hbase[node * HID + lane] = acc;
    hin[node * HID + lane] = acc;
  }
}

// ---------------- LN + xp = hn@Wp^T, xn = hn@Wn^T ----------------
__global__ __launch_bounds__(256) void convpre_kernel(
    const float* __restrict__ hin, const float* __restrict__ Wp, const float* __restrict__ Wn,
    const float* __restrict__ gamma, const float* __restrict__ beta,
    float* __restrict__ xp, float* __restrict__ xn){
  __shared__ float wpt[HID * HID];
  __shared__ float wnt[HID * HID];
  for (int i = threadIdx.x; i < HID * HID; i += 256){
    int j = i >> 6, k = i & 63;
    wpt[k * HID + j] = Wp[i];
    wnt[k * HID + j] = Wn[i];
  }
  __syncthreads();
  int lane = threadIdx.x & 63, wid = threadIdx.x >> 6;
  int gw = blockIdx.x * 4 + wid, nw = gridDim.x * 4;
  float g = gamma[lane], bt = beta[lane];
  for (int node = gw; node < N_NODES; node += nw){
    float v = hin[node * HID + lane];
    float s = v, s2 = v * v;
    #pragma unroll
    for (int d = 1; d < 64; d <<= 1){
      s  += __shfl_xor(s, d);
      s2 += __shfl_xor(s2, d);
    }
    float mu  = s * (1.0f / 64.0f);
    float var = s2 * (1.0f / 64.0f) - mu * mu;
    float hn  = (v - mu) * rsqrtf(var + LN_EPS) * g + bt;
    float ap = 0.f, an = 0.f;
    #pragma unroll
    for (int k = 0; k < 64; ++k){
      float hk = bcastf(hn, k);
      ap += hk * wpt[k * HID + lane];
      an += hk * wnt[k * HID + lane];
    }
    xp[node * HID + lane] = ap;
    xn[node * HID + lane] = an;
  }
}

// ---------------- gather: out[i] = dinv_i * sum_e dinv_s * x[s] + dinv_i^2 * x[i] + b ----------------
__global__ __launch_bounds__(256) void gather_kernel(
    const float* __restrict__ xpg, const float* __restrict__ xng,
    const int* __restrict__ cs_p, const float* __restrict__ cw_p,
    const int* __restrict__ off_p, const float* __restrict__ dinv_p, const float* __restrict__ bp,
    const int* __restrict__ cs_n, const float* __restrict__ cw_n,
    const int* __restrict__ off_n, const float* __restrict__ dinv_n, const float* __restrict__ bn,
    float* __restrict__ hp_out, float* __restrict__ hn_out){
  int lane = threadIdx.x & 63, wid = threadIdx.x >> 6;
  int gw = blockIdx.x * 4 + wid;
  bool negside = gw >= N_NODES;
  int node = negside ? gw - N_NODES : gw;
  const float* x  = negside ? xng   : xpg;
  const int*   cs = negside ? cs_n  : cs_p;
  const float* cw = negside ? cw_n  : cw_p;
  const int*   off= negside ? off_n : off_p;
  const float* dv = negside ? dinv_n: dinv_p;
  const float* b  = negside ? bn    : bp;
  float* out      = negside ? hn_out: hp_out;

  int s0 = off[node], s1 = off[node + 1];
  float acc = 0.f;
  for (int base = s0; base < s1; base += 64){
    int j = base + lane;
    int si = 0; float wi = 0.f;
    if (j < s1){ si = cs[j]; wi = cw[j]; }
    int cnt = min(64, s1 - base);
    for (int t = 0; t < cnt; ++t){
      int   ss = __shfl(si, t);
      float ww = __shfl(wi, t);
      acc += ww * x[ss * HID + lane];
    }
  }
  float di = dv[node];
  out[node * HID + lane] = di * acc + di * di * x[node * HID + lane] + b[lane];
}

// ---------------- psi + RK4 stage update ----------------
// mode 0: acc = delta;              hin = hbase + cmul*dt*delta
// mode 1: acc += waccmul*delta;     hin = hbase + cmul*dt*delta
// mode 2: h = hbase + dt/6*(acc+delta) -> hout & hin
__global__ __launch_bounds__(256) void psi_kernel(
    const float* __restrict__ hp, const float* __restrict__ hnn,
    const float* __restrict__ Wa, const float* __restrict__ ba,
    const float* __restrict__ Wb, const float* __restrict__ bb,
    const float* __restrict__ tvec,
    const float* __restrict__ hbase, float* __restrict__ acc,
    float* __restrict__ hin, float* __restrict__ hout,
    float cmul, float waccmul, int mode){
  __shared__ float wat[HID * HID];
  __shared__ float wbt[HID * HID];
  for (int i = threadIdx.x; i < HID * HID; i += 256){
    int j = i >> 6, k = i & 63;
    wat[k * HID + j] = Wa[i];
    wbt[k * HID + j] = Wb[i];
  }
  __syncthreads();
  int lane = threadIdx.x & 63, wid = threadIdx.x >> 6;
  int gw = blockIdx.x * 4 + wid, nw = gridDim.x * 4;
  float dt = (tvec[1] - tvec[0]) * 0.5f;     // / RK4_STEPS
  float bsum = ba[lane] + bb[lane];
  for (int node = gw; node < N_NODES; node += nw){
    float va = hp[node * HID + lane];
    float vb = hnn[node * HID + lane];
    float da = 0.f, db = 0.f;
    #pragma unroll
    for (int k = 0; k < 64; ++k){
      da += bcastf(va, k) * wat[k * HID + lane];
      db += bcastf(vb, k) * wbt[k * HID + lane];
    }
    float delta = da + db + bsum;
    delta = fminf(fmaxf(delta, -50.f), 50.f);
    int ix = node * HID + lane;
    if (mode == 2){
      float nh = hbase[ix] + (dt * (1.0f / 6.0f)) * (acc[ix] + delta);
      hout[ix] = nh;
      hin[ix]  = nh;
    } else {
      float av = (mode == 0) ? delta : (acc[ix] + waccmul * delta);
      acc[ix] = av;
      hin[ix] = hbase[ix] + cmul * dt * delta;
    }
  }
}

extern "C" void kernel_launch(void* const* d_in, const int* in_sizes, int n_in,
                              void* d_out, int out_size, void* d_ws, size_t ws_size,
                              hipStream_t stream){
  const float* x     = (const float*)d_in[0];
  const int*   ep    = (const int*)d_in[1];
  const int*   en    = (const int*)d_in[2];
  const float* tvec  = (const float*)d_in[3];
  const float* W_enc = (const float*)d_in[4];
  const float* b_enc = (const float*)d_in[5];
  const float* W_pos = (const float*)d_in[6];
  const float* b_pos = (const float*)d_in[7];
  const float* W_neg = (const float*)d_in[8];
  const float* b_neg = (const float*)d_in[9];
  const float* W_pp  = (const float*)d_in[10];
  const float* b_pp  = (const float*)d_in[11];
  const float* W_pn  = (const float*)d_in[12];
  const float* b_pn  = (const float*)d_in[13];
  const float* gamma = (const float*)d_in[14];
  const float* beta  = (const float*)d_in[15];
  float* hbase = (float*)d_out;

  char* w = (char*)d_ws;
  auto alloc = [&](size_t bytes) -> char* {
    char* p = w;
    w += (bytes + 255) & ~(size_t)255;
    return p;
  };
  const size_t npad = ((size_t)N_NODES * 4 + 255) & ~(size_t)255;
  int*   cnt_p = (int*)alloc(N_NODES * 4);
  int*   cnt_n = (int*)alloc(N_NODES * 4);
  int*   cur_p = (int*)alloc(N_NODES * 4);
  int*   cur_n = (int*)alloc(N_NODES * 4);
  size_t zero_span = 4 * npad;               // cnt_p..cur_n contiguous
  int*   off_p = (int*)alloc((N_NODES + 1) * 4);
  int*   off_n = (int*)alloc((N_NODES + 1) * 4);
  float* dinv_p= (float*)alloc(N_NODES * 4);
  float* dinv_n= (float*)alloc(N_NODES * 4);
  int*   cs_p  = (int*)alloc((size_t)N_EDGES * 4);
  float* cw_p  = (float*)alloc((size_t)N_EDGES * 4);
  int*   cs_n  = (int*)alloc((size_t)N_EDGES * 4);
  float* cw_n  = (float*)alloc((size_t)N_EDGES * 4);
  float* hin   = (float*)alloc((size_t)N_NODES * HID * 4);
  float* accb  = (float*)alloc((size_t)N_NODES * HID * 4);
  float* xp    = (float*)alloc((size_t)N_NODES * HID * 4);
  float* xn    = (float*)alloc((size_t)N_NODES * HID * 4);
  float* hp    = (float*)alloc((size_t)N_NODES * HID * 4);
  float* hnn   = (float*)alloc((size_t)N_NODES * HID * 4);

  hipMemsetAsync(cnt_p, 0, zero_span, stream);

  dim3 blk(256);
  count_kernel<<<(2 * N_EDGES + 255) / 256, blk, 0, stream>>>(ep, en, cnt_p, cnt_n);
  scan2_kernel<<<1, 1024, 0, stream>>>(cnt_p, off_p, cnt_n, off_n);
  dinv_kernel<<<(N_NODES + 255) / 256, blk, 0, stream>>>(cnt_p, cnt_n, dinv_p, dinv_n);
  fill_kernel<<<(2 * N_EDGES + 255) / 256, blk, 0, stream>>>(
      ep, en, off_p, off_n, cur_p, cur_n, dinv_p, dinv_n, cs_p, cw_p, cs_n, cw_n);
  encoder_kernel<<<1024, blk, 0, stream>>>(x, W_enc, b_enc, hbase, hin);

  const float stage_c[4] = {0.5f, 0.5f, 1.0f, 0.f};
  for (int step = 0; step < 2; ++step){
    for (int st = 0; st < 4; ++st){
      convpre_kernel<<<1024, blk, 0, stream>>>(hin, W_pos, W_neg, gamma, beta, xp, xn);
      gather_kernel<<<(2 * N_NODES) / 4, blk, 0, stream>>>(
          xp, xn, cs_p, cw_p, off_p, dinv_p, b_pos,
          cs_n, cw_n, off_n, dinv_n, b_neg, hp, hnn);
      int mode = (st == 0) ? 0 : (st == 3 ? 2 : 1);
      psi_kernel<<<1024, blk, 0, stream>>>(hp, hnn, W_pp, b_pp, W_pn, b_pn, tvec,
                                           hbase, accb, hin, hbase,
                                           stage_c[st], 2.0f, mode);
    }
  }
}

// Round 2
// 2266.501 us; speedup vs baseline: 1.1995x; 1.1995x over previous
//
#include <hip/hip_runtime.h>

#define N_NODES 50000
#define N_FEAT  128
#define HID     64
#define N_EDGES 1600000
#define LN_EPS  1e-5f

__device__ __forceinline__ float bcastf(float v, int l){
  return __uint_as_float(__builtin_amdgcn_readlane(__float_as_uint(v), l));
}
__device__ __forceinline__ float bf2f(unsigned short u){
  return __uint_as_float(((unsigned)u) << 16);
}
__device__ __forceinline__ unsigned short f2bf(float f){
  unsigned u = __float_as_uint(f);
  unsigned r = (u + 0x7fff + ((u >> 16) & 1)) >> 16;   // round-nearest-even
  return (unsigned short)r;
}

// ---------------- setup: degree count ----------------
__global__ void count_kernel(const int* __restrict__ ep, const int* __restrict__ en,
                             int* __restrict__ cnt_p, int* __restrict__ cnt_n){
  int t = blockIdx.x * blockDim.x + threadIdx.x;
  if (t < N_EDGES){
    atomicAdd(&cnt_p[ep[N_EDGES + t]], 1);
  } else if (t < 2 * N_EDGES){
    int e = t - N_EDGES;
    atomicAdd(&cnt_n[en[N_EDGES + e]], 1);
  }
}

// ---------------- setup: exclusive scan (2 blocks, one array each) ----------------
__global__ void scan2_kernel(const int* __restrict__ c0, int* __restrict__ o0,
                             const int* __restrict__ c1, int* __restrict__ o1){
  __shared__ int wsum[16];
  __shared__ int wexcl[16];
  __shared__ int carry_s;
  const int tid = threadIdx.x;          // 1024 threads
  const int lane = tid & 63, wid = tid >> 6;
  const int* c = blockIdx.x ? c1 : c0;
  int* o = blockIdx.x ? o1 : o0;
  if (tid == 0) carry_s = 0;
  __syncthreads();
  for (int base = 0; base < N_NODES; base += 1024){
    int idx = base + tid;
    int v = (idx < N_NODES) ? c[idx] : 0;
    int x = v;
    #pragma unroll
    for (int d = 1; d < 64; d <<= 1){
      int y = __shfl_up(x, d);
      if (lane >= d) x += y;
    }
    if (lane == 63) wsum[wid] = x;
    __syncthreads();
    int block_total = 0;
    if (tid == 0){
      int s = 0;
      for (int wv = 0; wv < 16; ++wv){ wexcl[wv] = s; s += wsum[wv]; }
      block_total = s;
    }
    __syncthreads();
    if (idx < N_NODES) o[idx] = carry_s + wexcl[wid] + (x - v);
    __syncthreads();
    if (tid == 0) carry_s += block_total;
    __syncthreads();
  }
  if (tid == 0) o[N_NODES] = carry_s;
}

// ---------------- setup: dinv = rsqrt(indeg + 1) ----------------
__global__ void dinv_kernel(const int* __restrict__ cnt_p, const int* __restrict__ cnt_n,
                            float* __restrict__ dp, float* __restrict__ dn){
  int i = blockIdx.x * blockDim.x + threadIdx.x;
  if (i < N_NODES){
    dp[i] = rsqrtf((float)(cnt_p[i] + 1));
    dn[i] = rsqrtf((float)(cnt_n[i] + 1));
  }
}

// ---------------- setup: CSR fill (src only, ushort — ids < 65536) ----------------
__global__ void fill_kernel(const int* __restrict__ ep, const int* __restrict__ en,
                            const int* __restrict__ off_p, const int* __restrict__ off_n,
                            int* __restrict__ cur_p, int* __restrict__ cur_n,
                            unsigned short* __restrict__ cs_p, unsigned short* __restrict__ cs_n){
  int t = blockIdx.x * blockDim.x + threadIdx.x;
  if (t < N_EDGES){
    int s = ep[t], d = ep[N_EDGES + t];
    int p = atomicAdd(&cur_p[d], 1);
    cs_p[off_p[d] + p] = (unsigned short)s;
  } else if (t < 2 * N_EDGES){
    int e = t - N_EDGES;
    int s = en[e], d = en[N_EDGES + e];
    int p = atomicAdd(&cur_n[d], 1);
    cs_n[off_n[d] + p] = (unsigned short)s;
  }
}

// ---------------- encoder + LN + conv-pre (fused) ----------------
// hbase = x@Wenc^T + benc ; hn = LN(hbase) ; xs_* = bf16(dinv_*[i] * (hn@W_*^T))
__global__ __launch_bounds__(256) void enc_conv_kernel(
    const float* __restrict__ x, const float* __restrict__ Wenc, const float* __restrict__ benc,
    const float* __restrict__ Wp, const float* __restrict__ Wn,
    const float* __restrict__ gamma, const float* __restrict__ beta,
    const float* __restrict__ dinv_p, const float* __restrict__ dinv_n,
    float* __restrict__ hbase, unsigned short* __restrict__ xs_p, unsigned short* __restrict__ xs_n){
  __shared__ float wt[N_FEAT * HID];   // 32 KB: wt[k*64+j] = Wenc[j*128+k]
  __shared__ float wpt[HID * HID];     // 16 KB
  __shared__ float wnt[HID * HID];     // 16 KB
  for (int i = threadIdx.x; i < N_FEAT * HID; i += 256){
    int j = i >> 7, k = i & 127;
    wt[k * HID + j] = Wenc[i];
  }
  for (int i = threadIdx.x; i < HID * HID; i += 256){
    int j = i >> 6, k = i & 63;
    wpt[k * HID + j] = Wp[i];
    wnt[k * HID + j] = Wn[i];
  }
  __syncthreads();
  int lane = threadIdx.x & 63, wid = threadIdx.x >> 6;
  int gw = blockIdx.x * 4 + wid, nw = gridDim.x * 4;
  float g = gamma[lane], bt = beta[lane];
  for (int node = gw; node < N_NODES; node += nw){
    float xa = x[node * N_FEAT + lane];
    float xb = x[node * N_FEAT + 64 + lane];
    float h = benc[lane];
    #pragma unroll
    for (int k = 0; k < 64; ++k){
      h += bcastf(xa, k) * wt[k * HID + lane];
      h += bcastf(xb, k) * wt[(64 + k) * HID + lane];
    }
    hbase[node * HID + lane] = h;
    // LN
    float s = h, s2 = h * h;
    #pragma unroll
    for (int d = 1; d < 64; d <<= 1){ s += __shfl_xor(s, d); s2 += __shfl_xor(s2, d); }
    float mu = s * (1.0f / 64.0f);
    float var = s2 * (1.0f / 64.0f) - mu * mu;
    float hn = (h - mu) * rsqrtf(var + LN_EPS) * g + bt;
    float ap = 0.f, an = 0.f;
    #pragma unroll
    for (int k = 0; k < 64; ++k){
      float hk = bcastf(hn, k);
      ap += hk * wpt[k * HID + lane];
      an += hk * wnt[k * HID + lane];
    }
    xs_p[node * HID + lane] = f2bf(dinv_p[node] * ap);
    xs_n[node * HID + lane] = f2bf(dinv_n[node] * an);
  }
}

// ---------------- gather: out[i] = dinv_i * (sum_e xs[s] + xs[i]) + b ----------------
__global__ __launch_bounds__(256) void gather_kernel(
    const unsigned short* __restrict__ xs_p, const unsigned short* __restrict__ xs_n,
    const unsigned short* __restrict__ cs_p, const int* __restrict__ off_p,
    const float* __restrict__ dinv_p, const float* __restrict__ bp,
    const unsigned short* __restrict__ cs_n, const int* __restrict__ off_n,
    const float* __restrict__ dinv_n, const float* __restrict__ bn,
    float* __restrict__ hp_out, float* __restrict__ hn_out){
  int lane = threadIdx.x & 63, wid = threadIdx.x >> 6;
  int gw = blockIdx.x * 4 + wid;
  bool negside = gw >= N_NODES;
  int node = negside ? gw - N_NODES : gw;
  const unsigned short* xs = negside ? xs_n : xs_p;
  const unsigned short* cs = negside ? cs_n : cs_p;
  const int*   off = negside ? off_n : off_p;
  const float* dv  = negside ? dinv_n : dinv_p;
  const float* b   = negside ? bn : bp;
  float* out       = negside ? hn_out : hp_out;

  int s0 = off[node], s1 = off[node + 1];
  float acc0 = bf2f(xs[node * HID + lane]);    // self-loop term (pre-scaled)
  float acc1 = 0.f;
  for (int base = s0; base < s1; base += 64){
    int j = base + lane;
    int si = (j < s1) ? (int)cs[j] : 0;
    int cnt = min(64, s1 - base);
    int t = 0;
    for (; t + 1 < cnt; t += 2){
      int ss0 = __builtin_amdgcn_readlane(si, t);
      int ss1 = __builtin_amdgcn_readlane(si, t + 1);
      acc0 += bf2f(xs[ss0 * HID + lane]);
      acc1 += bf2f(xs[ss1 * HID + lane]);
    }
    if (t < cnt){
      int ss0 = __builtin_amdgcn_readlane(si, t);
      acc0 += bf2f(xs[ss0 * HID + lane]);
    }
  }
  out[node * HID + lane] = dv[node] * (acc0 + acc1) + b[lane];
}

// ---------------- psi + RK4 stage + (optional) LN + conv-pre for next stage ----------------
// st: 0..3 within RK4 step. emit=0 on the very last stage.
__global__ __launch_bounds__(256) void psi_conv_kernel(
    const float* __restrict__ hp, const float* __restrict__ hnn,
    const float* __restrict__ Wa, const float* __restrict__ ba,
    const float* __restrict__ Wb, const float* __restrict__ bb,
    const float* __restrict__ tvec,
    float* __restrict__ hbase, float* __restrict__ acc,
    const float* __restrict__ Wp, const float* __restrict__ Wn,
    const float* __restrict__ gamma, const float* __restrict__ beta,
    const float* __restrict__ dinv_p, const float* __restrict__ dinv_n,
    unsigned short* __restrict__ xs_p, unsigned short* __restrict__ xs_n,
    int st, int emit){
  __shared__ float wat[HID * HID];
  __shared__ float wbt[HID * HID];
  __shared__ float wpt[HID * HID];
  __shared__ float wnt[HID * HID];               // 64 KB total
  for (int i = threadIdx.x; i < HID * HID; i += 256){
    int j = i >> 6, k = i & 63;
    wat[k * HID + j] = Wa[i];
    wbt[k * HID + j] = Wb[i];
    wpt[k * HID + j] = Wp[i];
    wnt[k * HID + j] = Wn[i];
  }
  __syncthreads();
  int lane = threadIdx.x & 63, wid = threadIdx.x >> 6;
  int gw = blockIdx.x * 4 + wid, nw = gridDim.x * 4;
  float dt = (tvec[1] - tvec[0]) * 0.5f;         // /RK4_STEPS
  float bsum = ba[lane] + bb[lane];
  float g = gamma[lane], bt = beta[lane];
  for (int node = gw; node < N_NODES; node += nw){
    int ix = node * HID + lane;
    float va = hp[ix];
    float vb = hnn[ix];
    float da = 0.f, db = 0.f;
    #pragma unroll
    for (int k = 0; k < 64; ++k){
      da += bcastf(va, k) * wat[k * HID + lane];
      db += bcastf(vb, k) * wbt[k * HID + lane];
    }
    float delta = da + db + bsum;
    delta = fminf(fmaxf(delta, -50.f), 50.f);
    float hb = hbase[ix];
    float hin;
    if (st == 0){
      acc[ix] = delta;
      hin = hb + 0.5f * dt * delta;
    } else if (st == 1){
      acc[ix] += 2.0f * delta;
      hin = hb + 0.5f * dt * delta;
    } else if (st == 2){
      acc[ix] += 2.0f * delta;
      hin = hb + dt * delta;
    } else {
      hin = hb + (dt * (1.0f / 6.0f)) * (acc[ix] + delta);
      hbase[ix] = hin;
    }
    if (emit){
      float s = hin, s2 = hin * hin;
      #pragma unroll
      for (int d = 1; d < 64; d <<= 1){ s += __shfl_xor(s, d); s2 += __shfl_xor(s2, d); }
      float mu = s * (1.0f / 64.0f);
      float var = s2 * (1.0f / 64.0f) - mu * mu;
      float hn = (hin - mu) * rsqrtf(var + LN_EPS) * g + bt;
      float ap = 0.f, an = 0.f;
      #pragma unroll
      for (int k = 0; k < 64; ++k){
        float hk = bcastf(hn, k);
        ap += hk * wpt[k * HID + lane];
        an += hk * wnt[k * HID + lane];
      }
      xs_p[ix] = f2bf(dinv_p[node] * ap);
      xs_n[ix] = f2bf(dinv_n[node] * an);
    }
  }
}

extern "C" void kernel_launch(void* const* d_in, const int* in_sizes, int n_in,
                              void* d_out, int out_size, void* d_ws, size_t ws_size,
                              hipStream_t stream){
  const float* x     = (const float*)d_in[0];
  const int*   ep    = (const int*)d_in[1];
  const int*   en    = (const int*)d_in[2];
  const float* tvec  = (const float*)d_in[3];
  const float* W_enc = (const float*)d_in[4];
  const float* b_enc = (const float*)d_in[5];
  const float* W_pos = (const float*)d_in[6];
  const float* b_pos = (const float*)d_in[7];
  const float* W_neg = (const float*)d_in[8];
  const float* b_neg = (const float*)d_in[9];
  const float* W_pp  = (const float*)d_in[10];
  const float* b_pp  = (const float*)d_in[11];
  const float* W_pn  = (const float*)d_in[12];
  const float* b_pn  = (const float*)d_in[13];
  const float* gamma = (const float*)d_in[14];
  const float* beta  = (const float*)d_in[15];
  float* hbase = (float*)d_out;

  char* w = (char*)d_ws;
  auto alloc = [&](size_t bytes) -> char* {
    char* p = w;
    w += (bytes + 255) & ~(size_t)255;
    return p;
  };
  const size_t npad = ((size_t)N_NODES * 4 + 255) & ~(size_t)255;
  int*   cnt_p = (int*)alloc(N_NODES * 4);
  int*   cnt_n = (int*)alloc(N_NODES * 4);
  int*   cur_p = (int*)alloc(N_NODES * 4);
  int*   cur_n = (int*)alloc(N_NODES * 4);
  size_t zero_span = 4 * npad;               // cnt_p..cur_n contiguous
  int*   off_p = (int*)alloc((N_NODES + 1) * 4);
  int*   off_n = (int*)alloc((N_NODES + 1) * 4);
  float* dinv_p= (float*)alloc(N_NODES * 4);
  float* dinv_n= (float*)alloc(N_NODES * 4);
  unsigned short* cs_p = (unsigned short*)alloc((size_t)N_EDGES * 2);
  unsigned short* cs_n = (unsigned short*)alloc((size_t)N_EDGES * 2);
  unsigned short* xs_p = (unsigned short*)alloc((size_t)N_NODES * HID * 2);
  unsigned short* xs_n = (unsigned short*)alloc((size_t)N_NODES * HID * 2);
  float* hp    = (float*)alloc((size_t)N_NODES * HID * 4);
  float* hnn   = (float*)alloc((size_t)N_NODES * HID * 4);
  float* accb  = (float*)alloc((size_t)N_NODES * HID * 4);

  hipMemsetAsync(cnt_p, 0, zero_span, stream);

  dim3 blk(256);
  count_kernel<<<(2 * N_EDGES + 255) / 256, blk, 0, stream>>>(ep, en, cnt_p, cnt_n);
  scan2_kernel<<<2, 1024, 0, stream>>>(cnt_p, off_p, cnt_n, off_n);
  dinv_kernel<<<(N_NODES + 255) / 256, blk, 0, stream>>>(cnt_p, cnt_n, dinv_p, dinv_n);
  fill_kernel<<<(2 * N_EDGES + 255) / 256, blk, 0, stream>>>(
      ep, en, off_p, off_n, cur_p, cur_n, cs_p, cs_n);
  enc_conv_kernel<<<1024, blk, 0, stream>>>(
      x, W_enc, b_enc, W_pos, W_neg, gamma, beta, dinv_p, dinv_n, hbase, xs_p, xs_n);

  for (int s = 0; s < 8; ++s){
    gather_kernel<<<(2 * N_NODES) / 4, blk, 0, stream>>>(
        xs_p, xs_n, cs_p, off_p, dinv_p, b_pos,
        cs_n, off_n, dinv_n, b_neg, hp, hnn);
    psi_conv_kernel<<<1024, blk, 0, stream>>>(
        hp, hnn, W_pp, b_pp, W_pn, b_pn, tvec, hbase, accb,
        W_pos, W_neg, gamma, beta, dinv_p, dinv_n, xs_p, xs_n,
        s & 3, (s < 7) ? 1 : 0);
  }
}

// Round 3
// 1792.899 us; speedup vs baseline: 1.5164x; 1.2642x over previous
//
#include <hip/hip_runtime.h>

#define N_NODES 50000
#define N_FEAT  128
#define HID     64
#define N_EDGES 1600000
#define LN_EPS  1e-5f
#define NBIN    8
#define BIN_W   6250u            // nodes per bin (8*6250 = 50000 exactly)
#define CAPB    229376u          // per-bin record capacity = 112*2048 (mean 200K, 70 sigma)
#define SLOTS   112
#define CHUNKB  2048u

typedef unsigned int uint;

__device__ __forceinline__ float bcastf(float v, int l){
  return __uint_as_float(__builtin_amdgcn_readlane(__float_as_uint(v), l));
}
__device__ __forceinline__ unsigned short f2bf(float f){
  unsigned u = __float_as_uint(f);
  unsigned r = (u + 0x7fff + ((u >> 16) & 1)) >> 16;   // round-nearest-even
  return (unsigned short)r;
}
__device__ __forceinline__ void accum8(float* a, uint4 v){
  a[0] += __uint_as_float(v.x << 16);
  a[1] += __uint_as_float(v.x & 0xFFFF0000u);
  a[2] += __uint_as_float(v.y << 16);
  a[3] += __uint_as_float(v.y & 0xFFFF0000u);
  a[4] += __uint_as_float(v.z << 16);
  a[5] += __uint_as_float(v.z & 0xFFFF0000u);
  a[6] += __uint_as_float(v.w << 16);
  a[7] += __uint_as_float(v.w & 0xFFFF0000u);
}

// ---------------- phase A: bin edges by dst range, append-contiguous records ----------------
__global__ __launch_bounds__(256) void binA_kernel(
    const int* __restrict__ ep, const int* __restrict__ en,
    uint* __restrict__ bin_cur, uint* __restrict__ recs_p, uint* __restrict__ recs_n){
  __shared__ uint sh[8192];        // 32 KB
  __shared__ uint cnt[NBIN], gb[NBIN], rnk[NBIN];
  const int NBLK = (N_EDGES + 8191) / 8192;   // 196 per side
  int bid = blockIdx.x;
  int side = bid >= NBLK;
  const int* e = side ? en : ep;
  uint* recs = side ? recs_n : recs_p;
  uint* bcur = bin_cur + side * NBIN;
  int cbase = (side ? bid - NBLK : bid) * 8192;
  int tid = threadIdx.x;
  if (tid < NBIN){ cnt[tid] = 0; rnk[tid] = 0; }
  __syncthreads();
  for (int i = tid; i < 8192; i += 256){
    int t = cbase + i;
    uint r = 0xFFFFFFFFu;
    if (t < N_EDGES){
      uint s = (uint)e[t], d = (uint)e[N_EDGES + t];
      r = (d << 16) | s;
      atomicAdd(&cnt[d / BIN_W], 1u);
    }
    sh[i] = r;
  }
  __syncthreads();
  if (tid < NBIN) gb[tid] = atomicAdd(&bcur[tid], cnt[tid]);
  __syncthreads();
  for (int i = tid; i < 8192; i += 256){
    uint r = sh[i];
    if (r != 0xFFFFFFFFu){
      uint b = (r >> 16) / BIN_W;
      uint pos = gb[b] + atomicAdd(&rnk[b], 1u);
      recs[b * CAPB + pos] = r;
    }
  }
}

// ---------------- per-node degree count from binned records (bin-local atomics) ----------------
__global__ __launch_bounds__(256) void countB_kernel(
    const uint* __restrict__ bin_cur,
    const uint* __restrict__ recs_p, const uint* __restrict__ recs_n,
    int* __restrict__ cnt_p, int* __restrict__ cnt_n){
  int bid = blockIdx.x;
  int side = bid >= NBIN * SLOTS; int lb = side ? bid - NBIN * SLOTS : bid;
  int b = lb & (NBIN - 1), slot = lb >> 3;
  const uint* recs = (side ? recs_n : recs_p) + (uint)b * CAPB;
  int* cnt = side ? cnt_n : cnt_p;
  uint n = bin_cur[side * NBIN + b];
  for (uint s0 = (uint)slot * CHUNKB; s0 < n; s0 += (uint)SLOTS * CHUNKB){
    uint e0 = min(s0 + CHUNKB, n);
    for (uint i = s0 + threadIdx.x; i < e0; i += 256u)
      atomicAdd(&cnt[recs[i] >> 16], 1);
  }
}

// ---------------- per-bin exclusive scan (16 blocks: side*8+bin) ----------------
__global__ __launch_bounds__(1024) void scan16_kernel(
    const uint* __restrict__ bin_cur,
    const int* __restrict__ c0, int* __restrict__ o0,
    const int* __restrict__ c1, int* __restrict__ o1){
  __shared__ int wsum[16];
  __shared__ int wexcl[16];
  __shared__ int carry_s;
  int side = blockIdx.x >> 3, b = blockIdx.x & 7;
  const int* c = side ? c1 : c0;
  int* o = side ? o1 : o0;
  const uint* bc = bin_cur + side * NBIN;
  int tid = threadIdx.x, lane = tid & 63, wid = tid >> 6;
  if (tid == 0){
    int s = 0;
    for (int k = 0; k < b; ++k) s += (int)bc[k];
    carry_s = s;
  }
  __syncthreads();
  int lo = b * (int)BIN_W, hi = lo + (int)BIN_W;
  for (int base = lo; base < hi; base += 1024){
    int idx = base + tid;
    int v = (idx < hi) ? c[idx] : 0;
    int x = v;
    #pragma unroll
    for (int d = 1; d < 64; d <<= 1){
      int y = __shfl_up(x, d);
      if (lane >= d) x += y;
    }
    if (lane == 63) wsum[wid] = x;
    __syncthreads();
    int block_total = 0;
    if (tid == 0){
      int s = 0;
      for (int wv = 0; wv < 16; ++wv){ wexcl[wv] = s; s += wsum[wv]; }
      block_total = s;
    }
    __syncthreads();
    if (idx < hi) o[idx] = carry_s + wexcl[wid] + (x - v);
    __syncthreads();
    if (tid == 0) carry_s += block_total;
    __syncthreads();
  }
  if (b == 7 && tid == 0) o[N_NODES] = carry_s;
}

// ---------------- dinv + zero xs pad rows ----------------
__global__ void dinv_kernel(const int* __restrict__ cnt_p, const int* __restrict__ cnt_n,
                            float* __restrict__ dp, float* __restrict__ dn,
                            unsigned short* __restrict__ xs_p, unsigned short* __restrict__ xs_n){
  int i = blockIdx.x * blockDim.x + threadIdx.x;
  if (i < N_NODES){
    dp[i] = rsqrtf((float)(cnt_p[i] + 1));
    dn[i] = rsqrtf((float)(cnt_n[i] + 1));
  }
  if (i < HID){
    xs_p[(size_t)N_NODES * HID + i] = 0;
    xs_n[(size_t)N_NODES * HID + i] = 0;
  }
}

// ---------------- CSR fill from binned records (bin-XCD-local writes) ----------------
__global__ __launch_bounds__(256) void fillB_kernel(
    const uint* __restrict__ bin_cur,
    const uint* __restrict__ recs_p, const uint* __restrict__ recs_n,
    const int* __restrict__ off_p, const int* __restrict__ off_n,
    int* __restrict__ cur_p, int* __restrict__ cur_n,
    unsigned short* __restrict__ cs_p, unsigned short* __restrict__ cs_n){
  int bid = blockIdx.x;
  int side = bid >= NBIN * SLOTS; int lb = side ? bid - NBIN * SLOTS : bid;
  int b = lb & (NBIN - 1), slot = lb >> 3;
  const uint* recs = (side ? recs_n : recs_p) + (uint)b * CAPB;
  const int* off = side ? off_n : off_p;
  int* cur = side ? cur_n : cur_p;
  unsigned short* cs = side ? cs_n : cs_p;
  uint n = bin_cur[side * NBIN + b];
  for (uint s0 = (uint)slot * CHUNKB; s0 < n; s0 += (uint)SLOTS * CHUNKB){
    uint e0 = min(s0 + CHUNKB, n);
    for (uint i = s0 + threadIdx.x; i < e0; i += 256u){
      uint r = recs[i];
      int d = (int)(r >> 16), s = (int)(r & 0xFFFFu);
      int p = atomicAdd(&cur[d], 1);
      cs[off[d] + p] = (unsigned short)s;
    }
  }
}

// ---------------- encoder + LN + conv-pre (fused) ----------------
__global__ __launch_bounds__(256) void enc_conv_kernel(
    const float* __restrict__ x, const float* __restrict__ Wenc, const float* __restrict__ benc,
    const float* __restrict__ Wp, const float* __restrict__ Wn,
    const float* __restrict__ gamma, const float* __restrict__ beta,
    const float* __restrict__ dinv_p, const float* __restrict__ dinv_n,
    float* __restrict__ hbase, unsigned short* __restrict__ xs_p, unsigned short* __restrict__ xs_n){
  __shared__ float wt[N_FEAT * HID];
  __shared__ float wpt[HID * HID];
  __shared__ float wnt[HID * HID];
  for (int i = threadIdx.x; i < N_FEAT * HID; i += 256){
    int j = i >> 7, k = i & 127;
    wt[k * HID + j] = Wenc[i];
  }
  for (int i = threadIdx.x; i < HID * HID; i += 256){
    int j = i >> 6, k = i & 63;
    wpt[k * HID + j] = Wp[i];
    wnt[k * HID + j] = Wn[i];
  }
  __syncthreads();
  int lane = threadIdx.x & 63, wid = threadIdx.x >> 6;
  int gw = blockIdx.x * 4 + wid, nw = gridDim.x * 4;
  float g = gamma[lane], bt = beta[lane];
  for (int node = gw; node < N_NODES; node += nw){
    float xa = x[node * N_FEAT + lane];
    float xb = x[node * N_FEAT + 64 + lane];
    float h = benc[lane];
    #pragma unroll
    for (int k = 0; k < 64; ++k){
      h += bcastf(xa, k) * wt[k * HID + lane];
      h += bcastf(xb, k) * wt[(64 + k) * HID + lane];
    }
    hbase[node * HID + lane] = h;
    float s = h, s2 = h * h;
    #pragma unroll
    for (int d = 1; d < 64; d <<= 1){ s += __shfl_xor(s, d); s2 += __shfl_xor(s2, d); }
    float mu = s * (1.0f / 64.0f);
    float var = s2 * (1.0f / 64.0f) - mu * mu;
    float hn = (h - mu) * rsqrtf(var + LN_EPS) * g + bt;
    float ap = 0.f, an = 0.f;
    #pragma unroll
    for (int k = 0; k < 64; ++k){
      float hk = bcastf(hn, k);
      ap += hk * wpt[k * HID + lane];
      an += hk * wnt[k * HID + lane];
    }
    xs_p[node * HID + lane] = f2bf(dinv_p[node] * ap);
    xs_n[node * HID + lane] = f2bf(dinv_n[node] * an);
  }
}

// ---------------- gather: 8 groups x 8 lanes, 8 rows (1 KB) per wave-load ----------------
__global__ __launch_bounds__(256) void gather_kernel(
    const unsigned short* __restrict__ xs_p, const unsigned short* __restrict__ xs_n,
    const unsigned short* __restrict__ cs_p, const int* __restrict__ off_p,
    const float* __restrict__ dinv_p, const float* __restrict__ bp,
    const unsigned short* __restrict__ cs_n, const int* __restrict__ off_n,
    const float* __restrict__ dinv_n, const float* __restrict__ bn,
    float* __restrict__ hp_out, float* __restrict__ hn_out){
  int lane = threadIdx.x & 63, wid = threadIdx.x >> 6;
  int gw = blockIdx.x * 4 + wid;
  bool neg = gw >= N_NODES;
  int node = neg ? gw - N_NODES : gw;
  const unsigned short* xs = neg ? xs_n : xs_p;
  const unsigned short* cs = neg ? cs_n : cs_p;
  const int*   off = neg ? off_n : off_p;
  const float* dv  = neg ? dinv_n : dinv_p;
  const float* b   = neg ? bn : bp;
  float* out       = neg ? hn_out : hp_out;

  int g = lane >> 3, j = lane & 7;
  int rowoff = 8 * j;
  int s0 = off[node], s1 = off[node + 1];

  float acc[8] = {0,0,0,0,0,0,0,0};
  float acc2[8] = {0,0,0,0,0,0,0,0};
  {
    // self-loop row: counted once (group 0); other groups hit the zero pad row
    int sid = (g == 0) ? node : N_NODES;
    uint4 v = *(const uint4*)(xs + (size_t)sid * HID + rowoff);
    accum8(acc, v);
  }
  for (int base = s0; base < s1; base += 64){
    int jj = base + lane;
    int si = (jj < s1) ? (int)cs[jj] : N_NODES;   // pad -> zero row
    int cnt = min(64, s1 - base);
    int nt = (cnt + 7) >> 3;
    int t = 0;
    for (; t + 2 <= nt; t += 2){
      int sA = __shfl(si, 8 * t + g);
      int sB = __shfl(si, 8 * t + 8 + g);
      uint4 vA = *(const uint4*)(xs + (size_t)sA * HID + rowoff);
      uint4 vB = *(const uint4*)(xs + (size_t)sB * HID + rowoff);
      accum8(acc, vA);
      accum8(acc2, vB);
    }
    if (t < nt){
      int sA = __shfl(si, 8 * t + g);
      uint4 vA = *(const uint4*)(xs + (size_t)sA * HID + rowoff);
      accum8(acc, vA);
    }
  }
  float dvv = dv[node];
  #pragma unroll
  for (int i = 0; i < 8; ++i){
    float a = acc[i] + acc2[i];
    a += __shfl_xor(a, 8);
    a += __shfl_xor(a, 16);
    a += __shfl_xor(a, 32);
    acc[i] = a;
  }
  if (lane < 8){
    float4 b0 = *(const float4*)(b + 8 * lane);
    float4 b1 = *(const float4*)(b + 8 * lane + 4);
    float4 o0, o1;
    o0.x = dvv * acc[0] + b0.x; o0.y = dvv * acc[1] + b0.y;
    o0.z = dvv * acc[2] + b0.z; o0.w = dvv * acc[3] + b0.w;
    o1.x = dvv * acc[4] + b1.x; o1.y = dvv * acc[5] + b1.y;
    o1.z = dvv * acc[6] + b1.z; o1.w = dvv * acc[7] + b1.w;
    float* orow = out + (size_t)node * HID + 8 * lane;
    *(float4*)orow = o0;
    *(float4*)(orow + 4) = o1;
  }
}

// ---------------- psi + RK4 stage + LN + conv-pre for next stage ----------------
__global__ __launch_bounds__(256) void psi_conv_kernel(
    const float* __restrict__ hp, const float* __restrict__ hnn,
    const float* __restrict__ Wa, const float* __restrict__ ba,
    const float* __restrict__ Wb, const float* __restrict__ bb,
    const float* __restrict__ tvec,
    float* __restrict__ hbase, float* __restrict__ acc,
    const float* __restrict__ Wp, const float* __restrict__ Wn,
    const float* __restrict__ gamma, const float* __restrict__ beta,
    const float* __restrict__ dinv_p, const float* __restrict__ dinv_n,
    unsigned short* __restrict__ xs_p, unsigned short* __restrict__ xs_n,
    int st, int emit){
  __shared__ float wat[HID * HID];
  __shared__ float wbt[HID * HID];
  __shared__ float wpt[HID * HID];
  __shared__ float wnt[HID * HID];
  for (int i = threadIdx.x; i < HID * HID; i += 256){
    int j = i >> 6, k = i & 63;
    wat[k * HID + j] = Wa[i];
    wbt[k * HID + j] = Wb[i];
    wpt[k * HID + j] = Wp[i];
    wnt[k * HID + j] = Wn[i];
  }
  __syncthreads();
  int lane = threadIdx.x & 63, wid = threadIdx.x >> 6;
  int gw = blockIdx.x * 4 + wid, nw = gridDim.x * 4;
  float dt = (tvec[1] - tvec[0]) * 0.5f;
  float bsum = ba[lane] + bb[lane];
  float g = gamma[lane], bt = beta[lane];
  for (int node = gw; node < N_NODES; node += nw){
    int ix = node * HID + lane;
    float va = hp[ix];
    float vb = hnn[ix];
    float da = 0.f, db = 0.f;
    #pragma unroll
    for (int k = 0; k < 64; ++k){
      da += bcastf(va, k) * wat[k * HID + lane];
      db += bcastf(vb, k) * wbt[k * HID + lane];
    }
    float delta = da + db + bsum;
    delta = fminf(fmaxf(delta, -50.f), 50.f);
    float hb = hbase[ix];
    float hin;
    if (st == 0){
      acc[ix] = delta;
      hin = hb + 0.5f * dt * delta;
    } else if (st == 1){
      acc[ix] += 2.0f * delta;
      hin = hb + 0.5f * dt * delta;
    } else if (st == 2){
      acc[ix] += 2.0f * delta;
      hin = hb + dt * delta;
    } else {
      hin = hb + (dt * (1.0f / 6.0f)) * (acc[ix] + delta);
      hbase[ix] = hin;
    }
    if (emit){
      float s = hin, s2 = hin * hin;
      #pragma unroll
      for (int d = 1; d < 64; d <<= 1){ s += __shfl_xor(s, d); s2 += __shfl_xor(s2, d); }
      float mu = s * (1.0f / 64.0f);
      float var = s2 * (1.0f / 64.0f) - mu * mu;
      float hn = (hin - mu) * rsqrtf(var + LN_EPS) * g + bt;
      float ap = 0.f, an = 0.f;
      #pragma unroll
      for (int k = 0; k < 64; ++k){
        float hk = bcastf(hn, k);
        ap += hk * wpt[k * HID + lane];
        an += hk * wnt[k * HID + lane];
      }
      xs_p[ix] = f2bf(dinv_p[node] * ap);
      xs_n[ix] = f2bf(dinv_n[node] * an);
    }
  }
}

extern "C" void kernel_launch(void* const* d_in, const int* in_sizes, int n_in,
                              void* d_out, int out_size, void* d_ws, size_t ws_size,
                              hipStream_t stream){
  const float* x     = (const float*)d_in[0];
  const int*   ep    = (const int*)d_in[1];
  const int*   en    = (const int*)d_in[2];
  const float* tvec  = (const float*)d_in[3];
  const float* W_enc = (const float*)d_in[4];
  const float* b_enc = (const float*)d_in[5];
  const float* W_pos = (const float*)d_in[6];
  const float* b_pos = (const float*)d_in[7];
  const float* W_neg = (const float*)d_in[8];
  const float* b_neg = (const float*)d_in[9];
  const float* W_pp  = (const float*)d_in[10];
  const float* b_pp  = (const float*)d_in[11];
  const float* W_pn  = (const float*)d_in[12];
  const float* b_pn  = (const float*)d_in[13];
  const float* gamma = (const float*)d_in[14];
  const float* beta  = (const float*)d_in[15];
  float* hbase = (float*)d_out;

  char* w = (char*)d_ws;
  auto alloc = [&](size_t bytes) -> char* {
    char* p = w;
    w += (bytes + 255) & ~(size_t)255;
    return p;
  };
  const size_t npad = ((size_t)N_NODES * 4 + 255) & ~(size_t)255;
  int*   cnt_p = (int*)alloc(N_NODES * 4);
  int*   cnt_n = (int*)alloc(N_NODES * 4);
  int*   cur_p = (int*)alloc(N_NODES * 4);
  int*   cur_n = (int*)alloc(N_NODES * 4);
  uint*  bin_cur = (uint*)alloc(2 * NBIN * 4);      // contiguous with the above
  size_t zero_span = 4 * npad + 256;
  int*   off_p = (int*)alloc((N_NODES + 1) * 4);
  int*   off_n = (int*)alloc((N_NODES + 1) * 4);
  float* dinv_p= (float*)alloc(N_NODES * 4);
  float* dinv_n= (float*)alloc(N_NODES * 4);
  uint*  recs_p= (uint*)alloc((size_t)NBIN * CAPB * 4);
  uint*  recs_n= (uint*)alloc((size_t)NBIN * CAPB * 4);
  unsigned short* cs_p = (unsigned short*)alloc((size_t)N_EDGES * 2);
  unsigned short* cs_n = (unsigned short*)alloc((size_t)N_EDGES * 2);
  unsigned short* xs_p = (unsigned short*)alloc((size_t)(N_NODES + 1) * HID * 2);
  unsigned short* xs_n = (unsigned short*)alloc((size_t)(N_NODES + 1) * HID * 2);
  float* hp    = (float*)alloc((size_t)N_NODES * HID * 4);
  float* hnn   = (float*)alloc((size_t)N_NODES * HID * 4);
  float* accb  = (float*)alloc((size_t)N_NODES * HID * 4);

  hipMemsetAsync(cnt_p, 0, zero_span, stream);

  dim3 blk(256);
  const int NBLK_A = 2 * ((N_EDGES + 8191) / 8192);     // 392
  const int NBLK_B = 2 * NBIN * SLOTS;                  // 1792
  binA_kernel<<<NBLK_A, blk, 0, stream>>>(ep, en, bin_cur, recs_p, recs_n);
  countB_kernel<<<NBLK_B, blk, 0, stream>>>(bin_cur, recs_p, recs_n, cnt_p, cnt_n);
  scan16_kernel<<<16, 1024, 0, stream>>>(bin_cur, cnt_p, off_p, cnt_n, off_n);
  dinv_kernel<<<(N_NODES + 255) / 256, blk, 0, stream>>>(cnt_p, cnt_n, dinv_p, dinv_n, xs_p, xs_n);
  fillB_kernel<<<NBLK_B, blk, 0, stream>>>(bin_cur, recs_p, recs_n, off_p, off_n,
                                           cur_p, cur_n, cs_p, cs_n);
  enc_conv_kernel<<<1024, blk, 0, stream>>>(
      x, W_enc, b_enc, W_pos, W_neg, gamma, beta, dinv_p, dinv_n, hbase, xs_p, xs_n);

  for (int s = 0; s < 8; ++s){
    gather_kernel<<<(2 * N_NODES) / 4, blk, 0, stream>>>(
        xs_p, xs_n, cs_p, off_p, dinv_p, b_pos,
        cs_n, off_n, dinv_n, b_neg, hp, hnn);
    psi_conv_kernel<<<1024, blk, 0, stream>>>(
        hp, hnn, W_pp, b_pp, W_pn, b_pn, tvec, hbase, accb,
        W_pos, W_neg, gamma, beta, dinv_p, dinv_n, xs_p, xs_n,
        s & 3, (s < 7) ? 1 : 0);
  }
}

// Round 4
// 1224.230 us; speedup vs baseline: 2.2207x; 1.4645x over previous
//
#include <hip/hip_runtime.h>

#define N_NODES 50000
#define N_FEAT  128
#define HID     64
#define N_EDGES 1600000
#define LN_EPS  1e-5f
#define NBIN    8
#define BIN_W   6250u
#define CAPB    229376u
#define SLOTS   112
#define CHUNKB  2048u

typedef unsigned int uint;

__device__ __forceinline__ float bcastf(float v, int l){
  return __uint_as_float(__builtin_amdgcn_readlane(__float_as_uint(v), l));
}
__device__ __forceinline__ unsigned short f2bf(float f){
  unsigned u = __float_as_uint(f);
  unsigned r = (u + 0x7fff + ((u >> 16) & 1)) >> 16;
  return (unsigned short)r;
}
__device__ __forceinline__ void accum8(float* a, uint4 v){
  a[0] += __uint_as_float(v.x << 16);
  a[1] += __uint_as_float(v.x & 0xFFFF0000u);
  a[2] += __uint_as_float(v.y << 16);
  a[3] += __uint_as_float(v.y & 0xFFFF0000u);
  a[4] += __uint_as_float(v.z << 16);
  a[5] += __uint_as_float(v.z & 0xFFFF0000u);
  a[6] += __uint_as_float(v.w << 16);
  a[7] += __uint_as_float(v.w & 0xFFFF0000u);
}

// ---------------- precompute: Wc = Wpsi @ W, bc = combined bias ----------------
__global__ void prep_kernel(const float* __restrict__ Wpp, const float* __restrict__ Wp,
                            const float* __restrict__ Wpn, const float* __restrict__ Wn,
                            const float* __restrict__ bp, const float* __restrict__ bpp,
                            const float* __restrict__ bn, const float* __restrict__ bpn,
                            float* __restrict__ Wc_p, float* __restrict__ Wc_n,
                            float* __restrict__ bc){
  int idx = blockIdx.x * blockDim.x + threadIdx.x;
  if (idx < 4096){
    int j = idx >> 6, k = idx & 63;
    float sp = 0.f, sn = 0.f;
    for (int m = 0; m < 64; ++m){
      sp += Wpp[j * 64 + m] * Wp[m * 64 + k];
      sn += Wpn[j * 64 + m] * Wn[m * 64 + k];
    }
    Wc_p[idx] = sp; Wc_n[idx] = sn;
  } else if (idx < 4160){
    int j = idx - 4096;
    float s = bpp[j] + bpn[j];
    for (int m = 0; m < 64; ++m) s += Wpp[j * 64 + m] * bp[m] + Wpn[j * 64 + m] * bn[m];
    bc[j] = s;
  }
}

// ---------------- phase A: bin edges by dst range ----------------
__global__ __launch_bounds__(256) void binA_kernel(
    const int* __restrict__ ep, const int* __restrict__ en,
    uint* __restrict__ bin_cur, uint* __restrict__ recs_p, uint* __restrict__ recs_n){
  __shared__ uint sh[8192];
  __shared__ uint cnt[NBIN], gb[NBIN], rnk[NBIN];
  const int NBLK = (N_EDGES + 8191) / 8192;
  int bid = blockIdx.x;
  int side = bid >= NBLK;
  const int* e = side ? en : ep;
  uint* recs = side ? recs_n : recs_p;
  uint* bcur = bin_cur + side * NBIN;
  int cbase = (side ? bid - NBLK : bid) * 8192;
  int tid = threadIdx.x;
  if (tid < NBIN){ cnt[tid] = 0; rnk[tid] = 0; }
  __syncthreads();
  for (int i = tid; i < 8192; i += 256){
    int t = cbase + i;
    uint r = 0xFFFFFFFFu;
    if (t < N_EDGES){
      uint s = (uint)e[t], d = (uint)e[N_EDGES + t];
      r = (d << 16) | s;
      atomicAdd(&cnt[d / BIN_W], 1u);
    }
    sh[i] = r;
  }
  __syncthreads();
  if (tid < NBIN) gb[tid] = atomicAdd(&bcur[tid], cnt[tid]);
  __syncthreads();
  for (int i = tid; i < 8192; i += 256){
    uint r = sh[i];
    if (r != 0xFFFFFFFFu){
      uint b = (r >> 16) / BIN_W;
      uint pos = gb[b] + atomicAdd(&rnk[b], 1u);
      recs[b * CAPB + pos] = r;
    }
  }
}

__global__ __launch_bounds__(256) void countB_kernel(
    const uint* __restrict__ bin_cur,
    const uint* __restrict__ recs_p, const uint* __restrict__ recs_n,
    int* __restrict__ cnt_p, int* __restrict__ cnt_n){
  int bid = blockIdx.x;
  int side = bid >= NBIN * SLOTS; int lb = side ? bid - NBIN * SLOTS : bid;
  int b = lb & (NBIN - 1), slot = lb >> 3;
  const uint* recs = (side ? recs_n : recs_p) + (uint)b * CAPB;
  int* cnt = side ? cnt_n : cnt_p;
  uint n = bin_cur[side * NBIN + b];
  for (uint s0 = (uint)slot * CHUNKB; s0 < n; s0 += (uint)SLOTS * CHUNKB){
    uint e0 = min(s0 + CHUNKB, n);
    for (uint i = s0 + threadIdx.x; i < e0; i += 256u)
      atomicAdd(&cnt[recs[i] >> 16], 1);
  }
}

__global__ __launch_bounds__(1024) void scan16_kernel(
    const uint* __restrict__ bin_cur,
    const int* __restrict__ c0, int* __restrict__ o0,
    const int* __restrict__ c1, int* __restrict__ o1){
  __shared__ int wsum[16];
  __shared__ int wexcl[16];
  __shared__ int carry_s;
  int side = blockIdx.x >> 3, b = blockIdx.x & 7;
  const int* c = side ? c1 : c0;
  int* o = side ? o1 : o0;
  const uint* bcq = bin_cur + side * NBIN;
  int tid = threadIdx.x, lane = tid & 63, wid = tid >> 6;
  if (tid == 0){
    int s = 0;
    for (int k = 0; k < b; ++k) s += (int)bcq[k];
    carry_s = s;
  }
  __syncthreads();
  int lo = b * (int)BIN_W, hi = lo + (int)BIN_W;
  for (int base = lo; base < hi; base += 1024){
    int idx = base + tid;
    int v = (idx < hi) ? c[idx] : 0;
    int x = v;
    #pragma unroll
    for (int d = 1; d < 64; d <<= 1){
      int y = __shfl_up(x, d);
      if (lane >= d) x += y;
    }
    if (lane == 63) wsum[wid] = x;
    __syncthreads();
    int block_total = 0;
    if (tid == 0){
      int s = 0;
      for (int wv = 0; wv < 16; ++wv){ wexcl[wv] = s; s += wsum[wv]; }
      block_total = s;
    }
    __syncthreads();
    if (idx < hi) o[idx] = carry_s + wexcl[wid] + (x - v);
    __syncthreads();
    if (tid == 0) carry_s += block_total;
    __syncthreads();
  }
  if (b == 7 && tid == 0) o[N_NODES] = carry_s;
}

__global__ void dinv_kernel(const int* __restrict__ cnt_p, const int* __restrict__ cnt_n,
                            float* __restrict__ dp, float* __restrict__ dn,
                            unsigned short* __restrict__ xs_p, unsigned short* __restrict__ xs_n){
  int i = blockIdx.x * blockDim.x + threadIdx.x;
  if (i < N_NODES){
    dp[i] = rsqrtf((float)(cnt_p[i] + 1));
    dn[i] = rsqrtf((float)(cnt_n[i] + 1));
  }
  if (i < HID){
    xs_p[(size_t)N_NODES * HID + i] = 0;
    xs_n[(size_t)N_NODES * HID + i] = 0;
  }
}

__global__ __launch_bounds__(256) void fillB_kernel(
    const uint* __restrict__ bin_cur,
    const uint* __restrict__ recs_p, const uint* __restrict__ recs_n,
    const int* __restrict__ off_p, const int* __restrict__ off_n,
    int* __restrict__ cur_p, int* __restrict__ cur_n,
    unsigned short* __restrict__ cs_p, unsigned short* __restrict__ cs_n){
  int bid = blockIdx.x;
  int side = bid >= NBIN * SLOTS; int lb = side ? bid - NBIN * SLOTS : bid;
  int b = lb & (NBIN - 1), slot = lb >> 3;
  const uint* recs = (side ? recs_n : recs_p) + (uint)b * CAPB;
  const int* off = side ? off_n : off_p;
  int* cur = side ? cur_n : cur_p;
  unsigned short* cs = side ? cs_n : cs_p;
  uint n = bin_cur[side * NBIN + b];
  for (uint s0 = (uint)slot * CHUNKB; s0 < n; s0 += (uint)SLOTS * CHUNKB){
    uint e0 = min(s0 + CHUNKB, n);
    for (uint i = s0 + threadIdx.x; i < e0; i += 256u){
      uint r = recs[i];
      int d = (int)(r >> 16), s = (int)(r & 0xFFFFu);
      int p = atomicAdd(&cur[d], 1);
      cs[off[d] + p] = (unsigned short)s;
    }
  }
}

// ---------------- encoder: hbase = x@Wenc^T+b; hn = LN(hbase). Weights in VGPRs ----------------
__global__ __launch_bounds__(256) void enc_kernel(
    const float* __restrict__ x, const float* __restrict__ Wenc, const float* __restrict__ benc,
    const float* __restrict__ gamma, const float* __restrict__ beta,
    float* __restrict__ hbase, float* __restrict__ hn){
  int lane = threadIdx.x & 63, wid = threadIdx.x >> 6;
  float we[128];
  const float* wr = Wenc + lane * N_FEAT;
  #pragma unroll
  for (int k4 = 0; k4 < 32; ++k4){
    float4 v = *(const float4*)(wr + 4 * k4);
    we[4*k4] = v.x; we[4*k4+1] = v.y; we[4*k4+2] = v.z; we[4*k4+3] = v.w;
  }
  float bv = benc[lane], g = gamma[lane], bt = beta[lane];
  int gw = blockIdx.x * 4 + wid, nw = gridDim.x * 4;
  for (int p = gw; p < N_NODES / 2; p += nw){
    int n0 = 2 * p, n1 = n0 + 1;
    float xa0 = x[(size_t)n0 * N_FEAT + lane], xb0 = x[(size_t)n0 * N_FEAT + 64 + lane];
    float xa1 = x[(size_t)n1 * N_FEAT + lane], xb1 = x[(size_t)n1 * N_FEAT + 64 + lane];
    float h0 = bv, h1 = bv;
    #pragma unroll
    for (int k = 0; k < 64; ++k){
      h0 += bcastf(xa0, k) * we[k];
      h1 += bcastf(xa1, k) * we[k];
      h0 += bcastf(xb0, k) * we[64 + k];
      h1 += bcastf(xb1, k) * we[64 + k];
    }
    hbase[n0 * HID + lane] = h0;
    hbase[n1 * HID + lane] = h1;
    float s0 = h0, q0 = h0 * h0, s1 = h1, q1 = h1 * h1;
    #pragma unroll
    for (int d = 1; d < 64; d <<= 1){
      s0 += __shfl_xor(s0, d); q0 += __shfl_xor(q0, d);
      s1 += __shfl_xor(s1, d); q1 += __shfl_xor(q1, d);
    }
    float mu0 = s0 * (1.0f/64.0f), var0 = q0 * (1.0f/64.0f) - mu0 * mu0;
    float mu1 = s1 * (1.0f/64.0f), var1 = q1 * (1.0f/64.0f) - mu1 * mu1;
    hn[n0 * HID + lane] = (h0 - mu0) * rsqrtf(var0 + LN_EPS) * g + bt;
    hn[n1 * HID + lane] = (h1 - mu1) * rsqrtf(var1 + LN_EPS) * g + bt;
  }
}

// ---------------- conv: xs_* = bf16(dinv_* * (hn @ Wc_*^T)). Weights in VGPRs ----------------
__global__ __launch_bounds__(256) void conv_kernel(
    const float* __restrict__ hn, const float* __restrict__ Wc_p, const float* __restrict__ Wc_n,
    const float* __restrict__ dinv_p, const float* __restrict__ dinv_n,
    unsigned short* __restrict__ xs_p, unsigned short* __restrict__ xs_n){
  int lane = threadIdx.x & 63, wid = threadIdx.x >> 6;
  float wp[64], wn[64];
  const float* wpr = Wc_p + lane * HID;
  const float* wnr = Wc_n + lane * HID;
  #pragma unroll
  for (int k4 = 0; k4 < 16; ++k4){
    float4 a = *(const float4*)(wpr + 4 * k4);
    wp[4*k4] = a.x; wp[4*k4+1] = a.y; wp[4*k4+2] = a.z; wp[4*k4+3] = a.w;
    float4 b = *(const float4*)(wnr + 4 * k4);
    wn[4*k4] = b.x; wn[4*k4+1] = b.y; wn[4*k4+2] = b.z; wn[4*k4+3] = b.w;
  }
  int gw = blockIdx.x * 4 + wid, nw = gridDim.x * 4;
  for (int p = gw; p < N_NODES / 2; p += nw){
    int n0 = 2 * p, n1 = n0 + 1;
    float h0 = hn[n0 * HID + lane], h1 = hn[n1 * HID + lane];
    float ap0 = 0.f, an0 = 0.f, ap1 = 0.f, an1 = 0.f;
    #pragma unroll
    for (int k = 0; k < 64; ++k){
      float a = bcastf(h0, k), b = bcastf(h1, k);
      ap0 += a * wp[k]; an0 += a * wn[k];
      ap1 += b * wp[k]; an1 += b * wn[k];
    }
    xs_p[n0 * HID + lane] = f2bf(dinv_p[n0] * ap0);
    xs_n[n0 * HID + lane] = f2bf(dinv_n[n0] * an0);
    xs_p[n1 * HID + lane] = f2bf(dinv_p[n1] * ap1);
    xs_n[n1 * HID + lane] = f2bf(dinv_n[n1] * an1);
  }
}

// ---------------- one gather side: 8 groups x 8 lanes, returns reduced sums in acc[8] ----------------
__device__ __forceinline__ void gather_side(
    const unsigned short* __restrict__ xs, const unsigned short* __restrict__ cs,
    int s0, int s1, int node, int g, int rowoff, int lane, float* acc){
  float a2[8] = {0,0,0,0,0,0,0,0};
  int sid = (g == 0) ? node : N_NODES;
  accum8(acc, *(const uint4*)(xs + (size_t)sid * HID + rowoff));
  for (int base = s0; base < s1; base += 64){
    int jj = base + lane;
    int si = (jj < s1) ? (int)cs[jj] : N_NODES;
    int cnt = min(64, s1 - base);
    int nt = (cnt + 7) >> 3;
    int t = 0;
    for (; t + 2 <= nt; t += 2){
      int sA = __shfl(si, 8 * t + g);
      int sB = __shfl(si, 8 * t + 8 + g);
      uint4 vA = *(const uint4*)(xs + (size_t)sA * HID + rowoff);
      uint4 vB = *(const uint4*)(xs + (size_t)sB * HID + rowoff);
      accum8(acc, vA);
      accum8(a2, vB);
    }
    if (t < nt){
      int sA = __shfl(si, 8 * t + g);
      accum8(acc, *(const uint4*)(xs + (size_t)sA * HID + rowoff));
    }
  }
  #pragma unroll
  for (int i = 0; i < 8; ++i){
    float a = acc[i] + a2[i];
    a += __shfl_xor(a, 8);
    a += __shfl_xor(a, 16);
    a += __shfl_xor(a, 32);
    acc[i] = a;
  }
}

// ---------------- gather both sides + delta + RK4 + LN (fused) ----------------
__global__ __launch_bounds__(256) void gatherrk_kernel(
    const unsigned short* __restrict__ xs_p, const unsigned short* __restrict__ xs_n,
    const unsigned short* __restrict__ cs_p, const int* __restrict__ off_p,
    const float* __restrict__ dinv_p,
    const unsigned short* __restrict__ cs_n, const int* __restrict__ off_n,
    const float* __restrict__ dinv_n,
    const float* __restrict__ bc, const float* __restrict__ gamma, const float* __restrict__ beta,
    const float* __restrict__ tvec,
    float* __restrict__ hbase, float* __restrict__ acc, float* __restrict__ hn,
    int st, int emit){
  int lane = threadIdx.x & 63, wid = threadIdx.x >> 6;
  int node = blockIdx.x * 4 + wid;
  if (node >= N_NODES) return;
  int g = lane >> 3, j = lane & 7, rowoff = 8 * j;

  float ap[8] = {0,0,0,0,0,0,0,0};
  float an[8] = {0,0,0,0,0,0,0,0};
  gather_side(xs_p, cs_p, off_p[node], off_p[node + 1], node, g, rowoff, lane, ap);
  gather_side(xs_n, cs_n, off_n[node], off_n[node + 1], node, g, rowoff, lane, an);

  float dvp = dinv_p[node], dvn = dinv_n[node];
  float4 b0 = *(const float4*)(bc + rowoff);
  float4 b1 = *(const float4*)(bc + rowoff + 4);
  float bcv[8] = {b0.x, b0.y, b0.z, b0.w, b1.x, b1.y, b1.z, b1.w};

  size_t ix8 = (size_t)node * HID + rowoff;
  float4 h0 = *(const float4*)(hbase + ix8);
  float4 h1 = *(const float4*)(hbase + ix8 + 4);
  float hb[8] = {h0.x, h0.y, h0.z, h0.w, h1.x, h1.y, h1.z, h1.w};
  float av[8];
  if (st != 0){
    float4 a0 = *(const float4*)(acc + ix8);
    float4 a1 = *(const float4*)(acc + ix8 + 4);
    av[0]=a0.x; av[1]=a0.y; av[2]=a0.z; av[3]=a0.w;
    av[4]=a1.x; av[5]=a1.y; av[6]=a1.z; av[7]=a1.w;
  }
  float dt = (tvec[1] - tvec[0]) * 0.5f;
  float hv[8];
  #pragma unroll
  for (int i = 0; i < 8; ++i){
    float d = dvp * ap[i] + dvn * an[i] + bcv[i];
    d = fminf(fmaxf(d, -50.f), 50.f);
    if (st == 0){
      av[i] = d;
      hv[i] = hb[i] + 0.5f * dt * d;
    } else if (st == 1){
      av[i] += 2.0f * d;
      hv[i] = hb[i] + 0.5f * dt * d;
    } else if (st == 2){
      av[i] += 2.0f * d;
      hv[i] = hb[i] + dt * d;
    } else {
      hv[i] = hb[i] + (dt * (1.0f / 6.0f)) * (av[i] + d);
    }
  }
  if (g == 0){
    if (st < 3){
      float4 o0 = {av[0], av[1], av[2], av[3]};
      float4 o1 = {av[4], av[5], av[6], av[7]};
      *(float4*)(acc + ix8) = o0;
      *(float4*)(acc + ix8 + 4) = o1;
    } else {
      float4 o0 = {hv[0], hv[1], hv[2], hv[3]};
      float4 o1 = {hv[4], hv[5], hv[6], hv[7]};
      *(float4*)(hbase + ix8) = o0;
      *(float4*)(hbase + ix8 + 4) = o1;
    }
  }
  if (emit){
    float s = 0.f, q = 0.f;
    #pragma unroll
    for (int i = 0; i < 8; ++i){ s += hv[i]; q += hv[i] * hv[i]; }
    s += __shfl_xor(s, 1); q += __shfl_xor(q, 1);
    s += __shfl_xor(s, 2); q += __shfl_xor(q, 2);
    s += __shfl_xor(s, 4); q += __shfl_xor(q, 4);
    float mu = s * (1.0f / 64.0f);
    float var = q * (1.0f / 64.0f) - mu * mu;
    float rs = rsqrtf(var + LN_EPS);
    float4 g0 = *(const float4*)(gamma + rowoff);
    float4 g1 = *(const float4*)(gamma + rowoff + 4);
    float4 t0 = *(const float4*)(beta + rowoff);
    float4 t1 = *(const float4*)(beta + rowoff + 4);
    float gm[8] = {g0.x, g0.y, g0.z, g0.w, g1.x, g1.y, g1.z, g1.w};
    float bt[8] = {t0.x, t0.y, t0.z, t0.w, t1.x, t1.y, t1.z, t1.w};
    if (g == 0){
      float4 o0, o1;
      o0.x = (hv[0]-mu)*rs*gm[0]+bt[0]; o0.y = (hv[1]-mu)*rs*gm[1]+bt[1];
      o0.z = (hv[2]-mu)*rs*gm[2]+bt[2]; o0.w = (hv[3]-mu)*rs*gm[3]+bt[3];
      o1.x = (hv[4]-mu)*rs*gm[4]+bt[4]; o1.y = (hv[5]-mu)*rs*gm[5]+bt[5];
      o1.z = (hv[6]-mu)*rs*gm[6]+bt[6]; o1.w = (hv[7]-mu)*rs*gm[7]+bt[7];
      *(float4*)(hn + ix8) = o0;
      *(float4*)(hn + ix8 + 4) = o1;
    }
  }
}

extern "C" void kernel_launch(void* const* d_in, const int* in_sizes, int n_in,
                              void* d_out, int out_size, void* d_ws, size_t ws_size,
                              hipStream_t stream){
  const float* x     = (const float*)d_in[0];
  const int*   ep    = (const int*)d_in[1];
  const int*   en    = (const int*)d_in[2];
  const float* tvec  = (const float*)d_in[3];
  const float* W_enc = (const float*)d_in[4];
  const float* b_enc = (const float*)d_in[5];
  const float* W_pos = (const float*)d_in[6];
  const float* b_pos = (const float*)d_in[7];
  const float* W_neg = (const float*)d_in[8];
  const float* b_neg = (const float*)d_in[9];
  const float* W_pp  = (const float*)d_in[10];
  const float* b_pp  = (const float*)d_in[11];
  const float* W_pn  = (const float*)d_in[12];
  const float* b_pn  = (const float*)d_in[13];
  const float* gamma = (const float*)d_in[14];
  const float* beta  = (const float*)d_in[15];
  float* hbase = (float*)d_out;

  char* w = (char*)d_ws;
  auto alloc = [&](size_t bytes) -> char* {
    char* p = w;
    w += (bytes + 255) & ~(size_t)255;
    return p;
  };
  const size_t npad = ((size_t)N_NODES * 4 + 255) & ~(size_t)255;
  int*   cnt_p = (int*)alloc(N_NODES * 4);
  int*   cnt_n = (int*)alloc(N_NODES * 4);
  int*   cur_p = (int*)alloc(N_NODES * 4);
  int*   cur_n = (int*)alloc(N_NODES * 4);
  uint*  bin_cur = (uint*)alloc(2 * NBIN * 4);
  size_t zero_span = 4 * npad + 256;
  int*   off_p = (int*)alloc((N_NODES + 1) * 4);
  int*   off_n = (int*)alloc((N_NODES + 1) * 4);
  float* dinv_p= (float*)alloc(N_NODES * 4);
  float* dinv_n= (float*)alloc(N_NODES * 4);
  uint*  recs_p= (uint*)alloc((size_t)NBIN * CAPB * 4);
  uint*  recs_n= (uint*)alloc((size_t)NBIN * CAPB * 4);
  unsigned short* cs_p = (unsigned short*)alloc((size_t)N_EDGES * 2);
  unsigned short* cs_n = (unsigned short*)alloc((size_t)N_EDGES * 2);
  unsigned short* xs_p = (unsigned short*)alloc((size_t)(N_NODES + 1) * HID * 2);
  unsigned short* xs_n = (unsigned short*)alloc((size_t)(N_NODES + 1) * HID * 2);
  float* hn    = (float*)alloc((size_t)N_NODES * HID * 4);
  float* accb  = (float*)alloc((size_t)N_NODES * HID * 4);
  float* Wc_p  = (float*)alloc(HID * HID * 4);
  float* Wc_n  = (float*)alloc(HID * HID * 4);
  float* bc    = (float*)alloc(HID * 4);

  hipMemsetAsync(cnt_p, 0, zero_span, stream);

  dim3 blk(256);
  const int NBLK_A = 2 * ((N_EDGES + 8191) / 8192);
  const int NBLK_B = 2 * NBIN * SLOTS;
  prep_kernel<<<17, blk, 0, stream>>>(W_pp, W_pos, W_pn, W_neg, b_pos, b_pp, b_neg, b_pn,
                                      Wc_p, Wc_n, bc);
  binA_kernel<<<NBLK_A, blk, 0, stream>>>(ep, en, bin_cur, recs_p, recs_n);
  countB_kernel<<<NBLK_B, blk, 0, stream>>>(bin_cur, recs_p, recs_n, cnt_p, cnt_n);
  scan16_kernel<<<16, 1024, 0, stream>>>(bin_cur, cnt_p, off_p, cnt_n, off_n);
  dinv_kernel<<<(N_NODES + 255) / 256, blk, 0, stream>>>(cnt_p, cnt_n, dinv_p, dinv_n, xs_p, xs_n);
  fillB_kernel<<<NBLK_B, blk, 0, stream>>>(bin_cur, recs_p, recs_n, off_p, off_n,
                                           cur_p, cur_n, cs_p, cs_n);
  enc_kernel<<<1024, blk, 0, stream>>>(x, W_enc, b_enc, gamma, beta, hbase, hn);

  for (int s = 0; s < 8; ++s){
    conv_kernel<<<1024, blk, 0, stream>>>(hn, Wc_p, Wc_n, dinv_p, dinv_n, xs_p, xs_n);
    gatherrk_kernel<<<(N_NODES + 3) / 4, blk, 0, stream>>>(
        xs_p, xs_n, cs_p, off_p, dinv_p, cs_n, off_n, dinv_n,
        bc, gamma, beta, tvec, hbase, accb, hn, s & 3, (s < 7) ? 1 : 0);
  }
}

// Round 5
// 1095.353 us; speedup vs baseline: 2.4820x; 1.1177x over previous
//
#include <hip/hip_runtime.h>

#define N_NODES 50000
#define N_FEAT  128
#define HID     64
#define N_EDGES 1600000
#define LN_EPS  1e-5f
#define NB2     400          // bins per side
#define BW2     125          // nodes per bin (400*125 = 50000)
#define CAP2    5120u        // per-bin record capacity (mean 4000, +17 sigma)

typedef unsigned int uint;

__device__ __forceinline__ float bcastf(float v, int l){
  return __uint_as_float(__builtin_amdgcn_readlane(__float_as_uint(v), l));
}
__device__ __forceinline__ unsigned short f2bf(float f){
  unsigned u = __float_as_uint(f);
  unsigned r = (u + 0x7fff + ((u >> 16) & 1)) >> 16;
  return (unsigned short)r;
}
__device__ __forceinline__ void accum8(float* a, uint4 v){
  a[0] += __uint_as_float(v.x << 16);
  a[1] += __uint_as_float(v.x & 0xFFFF0000u);
  a[2] += __uint_as_float(v.y << 16);
  a[3] += __uint_as_float(v.y & 0xFFFF0000u);
  a[4] += __uint_as_float(v.z << 16);
  a[5] += __uint_as_float(v.z & 0xFFFF0000u);
  a[6] += __uint_as_float(v.w << 16);
  a[7] += __uint_as_float(v.w & 0xFFFF0000u);
}

// ---------------- precompute: Wc = Wpsi @ W, bc = combined bias, zero xs pad rows --------
__global__ void prep_kernel(const float* __restrict__ Wpp, const float* __restrict__ Wp,
                            const float* __restrict__ Wpn, const float* __restrict__ Wn,
                            const float* __restrict__ bp, const float* __restrict__ bpp,
                            const float* __restrict__ bn, const float* __restrict__ bpn,
                            float* __restrict__ Wc_p, float* __restrict__ Wc_n,
                            float* __restrict__ bc,
                            unsigned short* __restrict__ xs_p, unsigned short* __restrict__ xs_n){
  int idx = blockIdx.x * blockDim.x + threadIdx.x;
  if (idx < 4096){
    int j = idx >> 6, k = idx & 63;
    float sp = 0.f, sn = 0.f;
    for (int m = 0; m < 64; ++m){
      sp += Wpp[j * 64 + m] * Wp[m * 64 + k];
      sn += Wpn[j * 64 + m] * Wn[m * 64 + k];
    }
    Wc_p[idx] = sp; Wc_n[idx] = sn;
  } else if (idx < 4160){
    int j = idx - 4096;
    float s = bpp[j] + bpn[j];
    for (int m = 0; m < 64; ++m) s += Wpp[j * 64 + m] * bp[m] + Wpn[j * 64 + m] * bn[m];
    bc[j] = s;
  } else if (idx < 4224){
    xs_p[(size_t)N_NODES * HID + (idx - 4160)] = 0;
    xs_n[(size_t)N_NODES * HID + (idx - 4160)] = 0;
  }
}

// ---------------- phase A: bin edges by dst range (400 bins/side) ----------------
__global__ __launch_bounds__(256) void binA_kernel(
    const int* __restrict__ ep, const int* __restrict__ en,
    uint* __restrict__ bin_cur, uint* __restrict__ recs_p, uint* __restrict__ recs_n){
  __shared__ uint sh[8192];
  __shared__ uint cnt2[NB2], gb2[NB2], rnk2[NB2];
  const int NBLK = (N_EDGES + 8191) / 8192;
  int bid = blockIdx.x;
  int side = bid >= NBLK;
  const int* e = side ? en : ep;
  uint* recs = side ? recs_n : recs_p;
  uint* bcur = bin_cur + side * NB2;
  int cbase = (side ? bid - NBLK : bid) * 8192;
  int tid = threadIdx.x;
  for (int i = tid; i < NB2; i += 256){ cnt2[i] = 0; rnk2[i] = 0; }
  __syncthreads();
  for (int i = tid; i < 8192; i += 256){
    int t = cbase + i;
    uint r = 0xFFFFFFFFu;
    if (t < N_EDGES){
      uint s = (uint)e[t], d = (uint)e[N_EDGES + t];
      r = (d << 16) | s;
      atomicAdd(&cnt2[d / BW2], 1u);
    }
    sh[i] = r;
  }
  __syncthreads();
  for (int i = tid; i < NB2; i += 256) gb2[i] = atomicAdd(&bcur[i], cnt2[i]);
  __syncthreads();
  for (int i = tid; i < 8192; i += 256){
    uint r = sh[i];
    if (r != 0xFFFFFFFFu){
      uint b = (r >> 16) / BW2;
      uint pos = gb2[b] + atomicAdd(&rnk2[b], 1u);
      recs[b * CAP2 + pos] = r;
    }
  }
}

// ---------------- LDS-staged counting sort per bin: cnt, dinv, cs (coalesced) ------------
__global__ __launch_bounds__(256) void fillC_kernel(
    const uint* __restrict__ bin_cur,
    const uint* __restrict__ recs_p, const uint* __restrict__ recs_n,
    int* __restrict__ cnt_p, int* __restrict__ cnt_n,
    float* __restrict__ dinv_p, float* __restrict__ dinv_n,
    unsigned short* __restrict__ cs_p, unsigned short* __restrict__ cs_n){
  __shared__ int hist[128];
  __shared__ int curx[128];
  __shared__ unsigned short staged[CAP2];
  __shared__ uint base_s;
  int bid = blockIdx.x;
  int side = bid >= NB2; int b = side ? bid - NB2 : bid;
  const uint* recs = (side ? recs_n : recs_p) + (size_t)b * CAP2;
  int* cnt = side ? cnt_n : cnt_p;
  float* dinv = side ? dinv_n : dinv_p;
  unsigned short* cs = side ? cs_n : cs_p;
  int tid = threadIdx.x, lane = tid & 63, wid = tid >> 6;
  int nodebase = b * BW2;
  if (tid < 128) hist[tid] = 0;
  __syncthreads();
  uint n = bin_cur[side * NB2 + b];
  if (wid == 1){                        // wave-parallel output base = prefix of bin counts
    uint s = 0;
    for (int k = lane; k < b; k += 64) s += bin_cur[side * NB2 + k];
    #pragma unroll
    for (int d = 1; d < 64; d <<= 1) s += __shfl_xor(s, d);
    if (lane == 0) base_s = s;
  }
  for (uint i = tid; i < n; i += 256)
    atomicAdd(&hist[(recs[i] >> 16) - nodebase], 1);
  __syncthreads();
  if (tid < BW2){
    int c = hist[tid];
    cnt[nodebase + tid] = c;
    dinv[nodebase + tid] = rsqrtf((float)(c + 1));
  }
  if (wid == 0){                        // exclusive scan hist -> curx
    int carry = 0;
    #pragma unroll
    for (int base = 0; base < BW2; base += 64){
      int idx = base + lane;
      int v = (idx < BW2) ? hist[idx] : 0;
      int x = v;
      #pragma unroll
      for (int d = 1; d < 64; d <<= 1){
        int y = __shfl_up(x, d);
        if (lane >= d) x += y;
      }
      if (idx < BW2) curx[idx] = carry + x - v;
      carry += bcastf(__int_as_float(x), 63) == 0.f ? 0 : 0;  // placeholder avoided below
      carry += 0;
      int tot = __shfl(x, 63);
      carry = carry + tot;
    }
  }
  __syncthreads();
  for (uint i = tid; i < n; i += 256){
    uint r = recs[i];
    int d = (int)(r >> 16) - nodebase;
    int p = atomicAdd(&curx[d], 1);
    staged[p] = (unsigned short)(r & 0xFFFFu);
  }
  __syncthreads();
  uint base = base_s;
  for (uint i = tid; i < n; i += 256) cs[base + i] = staged[i];
}

// ---------------- per-side scan of cnt -> off (16 blocks: side*8+segment) ----------------
__global__ __launch_bounds__(1024) void scan16_kernel(
    const uint* __restrict__ bin_cur,
    const int* __restrict__ c0, int* __restrict__ o0,
    const int* __restrict__ c1, int* __restrict__ o1){
  __shared__ int wsum[16];
  __shared__ int wexcl[16];
  __shared__ int carry_s;
  int side = blockIdx.x >> 3, b = blockIdx.x & 7;
  const int* c = side ? c1 : c0;
  int* o = side ? o1 : o0;
  int tid = threadIdx.x, lane = tid & 63, wid = tid >> 6;
  if (wid == 0){                        // carry = records in bins below this segment (50 bins/seg)
    int s = 0;
    for (int k = lane; k < 50 * b; k += 64) s += (int)bin_cur[side * NB2 + k];
    #pragma unroll
    for (int d = 1; d < 64; d <<= 1) s += __shfl_xor(s, d);
    if (lane == 0) carry_s = s;
  }
  __syncthreads();
  int lo = b * 6250, hi = lo + 6250;
  for (int base = lo; base < hi; base += 1024){
    int idx = base + tid;
    int v = (idx < hi) ? c[idx] : 0;
    int x = v;
    #pragma unroll
    for (int d = 1; d < 64; d <<= 1){
      int y = __shfl_up(x, d);
      if (lane >= d) x += y;
    }
    if (lane == 63) wsum[wid] = x;
    __syncthreads();
    int block_total = 0;
    if (tid == 0){
      int s = 0;
      for (int wv = 0; wv < 16; ++wv){ wexcl[wv] = s; s += wsum[wv]; }
      block_total = s;
    }
    __syncthreads();
    if (idx < hi) o[idx] = carry_s + wexcl[wid] + (x - v);
    __syncthreads();
    if (tid == 0) carry_s += block_total;
    __syncthreads();
  }
  if (b == 7 && tid == 0) o[N_NODES] = carry_s;
}

// ---------------- encoder: hbase = x@Wenc^T+b; hn = LN(hbase). Weights in VGPRs ----------
__global__ __launch_bounds__(256) void enc_kernel(
    const float* __restrict__ x, const float* __restrict__ Wenc, const float* __restrict__ benc,
    const float* __restrict__ gamma, const float* __restrict__ beta,
    float* __restrict__ hbase, float* __restrict__ hn){
  int lane = threadIdx.x & 63, wid = threadIdx.x >> 6;
  float we[128];
  const float* wr = Wenc + lane * N_FEAT;
  #pragma unroll
  for (int k4 = 0; k4 < 32; ++k4){
    float4 v = *(const float4*)(wr + 4 * k4);
    we[4*k4] = v.x; we[4*k4+1] = v.y; we[4*k4+2] = v.z; we[4*k4+3] = v.w;
  }
  float bv = benc[lane], g = gamma[lane], bt = beta[lane];
  int gw = blockIdx.x * 4 + wid, nw = gridDim.x * 4;
  for (int p = gw; p < N_NODES / 2; p += nw){
    int n0 = 2 * p, n1 = n0 + 1;
    float xa0 = x[(size_t)n0 * N_FEAT + lane], xb0 = x[(size_t)n0 * N_FEAT + 64 + lane];
    float xa1 = x[(size_t)n1 * N_FEAT + lane], xb1 = x[(size_t)n1 * N_FEAT + 64 + lane];
    float h0 = bv, h1 = bv;
    #pragma unroll
    for (int k = 0; k < 64; ++k){
      h0 += bcastf(xa0, k) * we[k];
      h1 += bcastf(xa1, k) * we[k];
      h0 += bcastf(xb0, k) * we[64 + k];
      h1 += bcastf(xb1, k) * we[64 + k];
    }
    hbase[n0 * HID + lane] = h0;
    hbase[n1 * HID + lane] = h1;
    float s0 = h0, q0 = h0 * h0, s1 = h1, q1 = h1 * h1;
    #pragma unroll
    for (int d = 1; d < 64; d <<= 1){
      s0 += __shfl_xor(s0, d); q0 += __shfl_xor(q0, d);
      s1 += __shfl_xor(s1, d); q1 += __shfl_xor(q1, d);
    }
    float mu0 = s0 * (1.0f/64.0f), var0 = q0 * (1.0f/64.0f) - mu0 * mu0;
    float mu1 = s1 * (1.0f/64.0f), var1 = q1 * (1.0f/64.0f) - mu1 * mu1;
    hn[n0 * HID + lane] = (h0 - mu0) * rsqrtf(var0 + LN_EPS) * g + bt;
    hn[n1 * HID + lane] = (h1 - mu1) * rsqrtf(var1 + LN_EPS) * g + bt;
  }
}

// ---------------- conv: xs_* = bf16(dinv_* * (hn @ Wc_*^T)). Weights in VGPRs ------------
__global__ __launch_bounds__(256) void conv_kernel(
    const float* __restrict__ hn, const float* __restrict__ Wc_p, const float* __restrict__ Wc_n,
    const float* __restrict__ dinv_p, const float* __restrict__ dinv_n,
    unsigned short* __restrict__ xs_p, unsigned short* __restrict__ xs_n){
  int lane = threadIdx.x & 63, wid = threadIdx.x >> 6;
  float wp[64], wn[64];
  const float* wpr = Wc_p + lane * HID;
  const float* wnr = Wc_n + lane * HID;
  #pragma unroll
  for (int k4 = 0; k4 < 16; ++k4){
    float4 a = *(const float4*)(wpr + 4 * k4);
    wp[4*k4] = a.x; wp[4*k4+1] = a.y; wp[4*k4+2] = a.z; wp[4*k4+3] = a.w;
    float4 b = *(const float4*)(wnr + 4 * k4);
    wn[4*k4] = b.x; wn[4*k4+1] = b.y; wn[4*k4+2] = b.z; wn[4*k4+3] = b.w;
  }
  int gw = blockIdx.x * 4 + wid, nw = gridDim.x * 4;
  for (int p = gw; p < N_NODES / 2; p += nw){
    int n0 = 2 * p, n1 = n0 + 1;
    float h0 = hn[n0 * HID + lane], h1 = hn[n1 * HID + lane];
    float ap0 = 0.f, an0 = 0.f, ap1 = 0.f, an1 = 0.f;
    #pragma unroll
    for (int k = 0; k < 64; ++k){
      float a = bcastf(h0, k), b = bcastf(h1, k);
      ap0 += a * wp[k]; an0 += a * wn[k];
      ap1 += b * wp[k]; an1 += b * wn[k];
    }
    xs_p[n0 * HID + lane] = f2bf(dinv_p[n0] * ap0);
    xs_n[n0 * HID + lane] = f2bf(dinv_n[n0] * an0);
    xs_p[n1 * HID + lane] = f2bf(dinv_p[n1] * ap1);
    xs_n[n1 * HID + lane] = f2bf(dinv_n[n1] * an1);
  }
}

// ---------------- slow-path accumulate (deg > 64), no self, no reduce --------------------
__device__ __forceinline__ void gather_side_acc(
    const unsigned short* __restrict__ xs, const unsigned short* __restrict__ cs,
    int s0, int s1, int g, int rowoff, int lane, float* acc){
  for (int base = s0; base < s1; base += 64){
    int jj = base + lane;
    int si = (jj < s1) ? (int)cs[jj] : N_NODES;
    int cnt = min(64, s1 - base);
    int nt = (cnt + 7) >> 3;
    for (int t = 0; t < nt; ++t){
      int r = __shfl(si, 8 * t + g);
      accum8(acc, *(const uint4*)(xs + (size_t)r * HID + rowoff));
    }
  }
}

// ---------------- gather both sides, 2 nodes/wave + delta + RK4 + LN (fused) -------------
__global__ __launch_bounds__(256) void gatherrk_kernel(
    const unsigned short* __restrict__ xs_p, const unsigned short* __restrict__ xs_n,
    const unsigned short* __restrict__ cs_p, const int* __restrict__ off_p,
    const float* __restrict__ dinv_p,
    const unsigned short* __restrict__ cs_n, const int* __restrict__ off_n,
    const float* __restrict__ dinv_n,
    const float* __restrict__ bc, const float* __restrict__ gamma, const float* __restrict__ beta,
    const float* __restrict__ tvec,
    float* __restrict__ hbase, float* __restrict__ acc, float* __restrict__ hn,
    int st, int emit){
  int lane = threadIdx.x & 63, wid = threadIdx.x >> 6;
  int pair = blockIdx.x * 4 + wid;
  int nA = 2 * pair, nB = nA + 1;
  if (nA >= N_NODES) return;
  int g = lane >> 3, j = lane & 7, rowoff = 8 * j;

  int pA0 = off_p[nA], pA1 = off_p[nA + 1], pB1 = off_p[nB + 1];
  int qA0 = off_n[nA], qA1 = off_n[nA + 1], qB1 = off_n[nB + 1];
  int dPA = pA1 - pA0, dPB = pB1 - pA1, dNA = qA1 - qA0, dNB = qB1 - qA1;

  float aPA[8] = {0,0,0,0,0,0,0,0};
  float aPB[8] = {0,0,0,0,0,0,0,0};
  float aNA[8] = {0,0,0,0,0,0,0,0};
  float aNB[8] = {0,0,0,0,0,0,0,0};
  // self rows (group 0 real, others hit zero pad row)
  accum8(aPA, *(const uint4*)(xs_p + (size_t)((g==0)?nA:N_NODES) * HID + rowoff));
  accum8(aPB, *(const uint4*)(xs_p + (size_t)((g==0)?nB:N_NODES) * HID + rowoff));
  accum8(aNA, *(const uint4*)(xs_n + (size_t)((g==0)?nA:N_NODES) * HID + rowoff));
  accum8(aNB, *(const uint4*)(xs_n + (size_t)((g==0)?nB:N_NODES) * HID + rowoff));

  if (dPA <= 64 && dPB <= 64 && dNA <= 64 && dNB <= 64){
    int siPA = (lane < dPA) ? (int)cs_p[pA0 + lane] : N_NODES;
    int siPB = (lane < dPB) ? (int)cs_p[pA1 + lane] : N_NODES;
    int siNA = (lane < dNA) ? (int)cs_n[qA0 + lane] : N_NODES;
    int siNB = (lane < dNB) ? (int)cs_n[qA1 + lane] : N_NODES;
    int dP = dPA > dPB ? dPA : dPB;
    int dN = dNA > dNB ? dNA : dNB;
    int ntP = (dP + 7) >> 3, ntN = (dN + 7) >> 3;
    for (int t = 0; t < ntP; t += 2){
      int gi0 = 8 * t + g, gi1 = gi0 + 8;
      int rA0 = __shfl(siPA, gi0), rB0 = __shfl(siPB, gi0);
      int rA1 = __shfl(siPA, gi1), rB1 = __shfl(siPB, gi1);
      uint4 vA0 = *(const uint4*)(xs_p + (size_t)rA0 * HID + rowoff);
      uint4 vB0 = *(const uint4*)(xs_p + (size_t)rB0 * HID + rowoff);
      uint4 vA1 = *(const uint4*)(xs_p + (size_t)rA1 * HID + rowoff);
      uint4 vB1 = *(const uint4*)(xs_p + (size_t)rB1 * HID + rowoff);
      accum8(aPA, vA0); accum8(aPB, vB0); accum8(aPA, vA1); accum8(aPB, vB1);
    }
    for (int t = 0; t < ntN; t += 2){
      int gi0 = 8 * t + g, gi1 = gi0 + 8;
      int rA0 = __shfl(siNA, gi0), rB0 = __shfl(siNB, gi0);
      int rA1 = __shfl(siNA, gi1), rB1 = __shfl(siNB, gi1);
      uint4 vA0 = *(const uint4*)(xs_n + (size_t)rA0 * HID + rowoff);
      uint4 vB0 = *(const uint4*)(xs_n + (size_t)rB0 * HID + rowoff);
      uint4 vA1 = *(const uint4*)(xs_n + (size_t)rA1 * HID + rowoff);
      uint4 vB1 = *(const uint4*)(xs_n + (size_t)rB1 * HID + rowoff);
      accum8(aNA, vA0); accum8(aNB, vB0); accum8(aNA, vA1); accum8(aNB, vB1);
    }
  } else {
    gather_side_acc(xs_p, cs_p, pA0, pA1, g, rowoff, lane, aPA);
    gather_side_acc(xs_p, cs_p, pA1, pB1, g, rowoff, lane, aPB);
    gather_side_acc(xs_n, cs_n, qA0, qA1, g, rowoff, lane, aNA);
    gather_side_acc(xs_n, cs_n, qA1, qB1, g, rowoff, lane, aNB);
  }
  #pragma unroll
  for (int i = 0; i < 8; ++i){
    float a = aPA[i]; a += __shfl_xor(a, 8); a += __shfl_xor(a, 16); a += __shfl_xor(a, 32); aPA[i] = a;
    float b = aPB[i]; b += __shfl_xor(b, 8); b += __shfl_xor(b, 16); b += __shfl_xor(b, 32); aPB[i] = b;
    float c = aNA[i]; c += __shfl_xor(c, 8); c += __shfl_xor(c, 16); c += __shfl_xor(c, 32); aNA[i] = c;
    float d = aNB[i]; d += __shfl_xor(d, 8); d += __shfl_xor(d, 16); d += __shfl_xor(d, 32); aNB[i] = d;
  }

  float dvpA = dinv_p[nA], dvnA = dinv_n[nA], dvpB = dinv_p[nB], dvnB = dinv_n[nB];
  float4 b0 = *(const float4*)(bc + rowoff);
  float4 b1 = *(const float4*)(bc + rowoff + 4);
  float bcv[8] = {b0.x, b0.y, b0.z, b0.w, b1.x, b1.y, b1.z, b1.w};

  size_t ixA = (size_t)nA * HID + rowoff, ixB = (size_t)nB * HID + rowoff;
  float4 hA0 = *(const float4*)(hbase + ixA), hA1 = *(const float4*)(hbase + ixA + 4);
  float4 hB0 = *(const float4*)(hbase + ixB), hB1 = *(const float4*)(hbase + ixB + 4);
  float hbA[8] = {hA0.x,hA0.y,hA0.z,hA0.w,hA1.x,hA1.y,hA1.z,hA1.w};
  float hbB[8] = {hB0.x,hB0.y,hB0.z,hB0.w,hB1.x,hB1.y,hB1.z,hB1.w};
  float avA[8], avB[8];
  if (st != 0){
    float4 aA0 = *(const float4*)(acc + ixA), aA1 = *(const float4*)(acc + ixA + 4);
    float4 aB0 = *(const float4*)(acc + ixB), aB1 = *(const float4*)(acc + ixB + 4);
    avA[0]=aA0.x; avA[1]=aA0.y; avA[2]=aA0.z; avA[3]=aA0.w;
    avA[4]=aA1.x; avA[5]=aA1.y; avA[6]=aA1.z; avA[7]=aA1.w;
    avB[0]=aB0.x; avB[1]=aB0.y; avB[2]=aB0.z; avB[3]=aB0.w;
    avB[4]=aB1.x; avB[5]=aB1.y; avB[6]=aB1.z; avB[7]=aB1.w;
  }
  float dt = (tvec[1] - tvec[0]) * 0.5f;
  float hvA[8], hvB[8];
  #pragma unroll
  for (int i = 0; i < 8; ++i){
    float dA = dvpA * aPA[i] + dvnA * aNA[i] + bcv[i];
    float dB = dvpB * aPB[i] + dvnB * aNB[i] + bcv[i];
    dA = fminf(fmaxf(dA, -50.f), 50.f);
    dB = fminf(fmaxf(dB, -50.f), 50.f);
    if (st == 0){
      avA[i] = dA; avB[i] = dB;
      hvA[i] = hbA[i] + 0.5f * dt * dA; hvB[i] = hbB[i] + 0.5f * dt * dB;
    } else if (st == 1){
      avA[i] += 2.0f * dA; avB[i] += 2.0f * dB;
      hvA[i] = hbA[i] + 0.5f * dt * dA; hvB[i] = hbB[i] + 0.5f * dt * dB;
    } else if (st == 2){
      avA[i] += 2.0f * dA; avB[i] += 2.0f * dB;
      hvA[i] = hbA[i] + dt * dA; hvB[i] = hbB[i] + dt * dB;
    } else {
      hvA[i] = hbA[i] + (dt * (1.0f/6.0f)) * (avA[i] + dA);
      hvB[i] = hbB[i] + (dt * (1.0f/6.0f)) * (avB[i] + dB);
    }
  }
  if (st < 3){
    if (g == 0){
      float4 o0 = {avA[0],avA[1],avA[2],avA[3]}, o1 = {avA[4],avA[5],avA[6],avA[7]};
      *(float4*)(acc + ixA) = o0; *(float4*)(acc + ixA + 4) = o1;
    } else if (g == 1){
      float4 o0 = {avB[0],avB[1],avB[2],avB[3]}, o1 = {avB[4],avB[5],avB[6],avB[7]};
      *(float4*)(acc + ixB) = o0; *(float4*)(acc + ixB + 4) = o1;
    }
  } else {
    if (g == 0){
      float4 o0 = {hvA[0],hvA[1],hvA[2],hvA[3]}, o1 = {hvA[4],hvA[5],hvA[6],hvA[7]};
      *(float4*)(hbase + ixA) = o0; *(float4*)(hbase + ixA + 4) = o1;
    } else if (g == 1){
      float4 o0 = {hvB[0],hvB[1],hvB[2],hvB[3]}, o1 = {hvB[4],hvB[5],hvB[6],hvB[7]};
      *(float4*)(hbase + ixB) = o0; *(float4*)(hbase + ixB + 4) = o1;
    }
  }
  if (emit){
    float sA = 0.f, qA = 0.f, sB = 0.f, qB = 0.f;
    #pragma unroll
    for (int i = 0; i < 8; ++i){
      sA += hvA[i]; qA += hvA[i] * hvA[i];
      sB += hvB[i]; qB += hvB[i] * hvB[i];
    }
    sA += __shfl_xor(sA, 1); qA += __shfl_xor(qA, 1);
    sA += __shfl_xor(sA, 2); qA += __shfl_xor(qA, 2);
    sA += __shfl_xor(sA, 4); qA += __shfl_xor(qA, 4);
    sB += __shfl_xor(sB, 1); qB += __shfl_xor(qB, 1);
    sB += __shfl_xor(sB, 2); qB += __shfl_xor(qB, 2);
    sB += __shfl_xor(sB, 4); qB += __shfl_xor(qB, 4);
    float muA = sA * (1.0f/64.0f), varA = qA * (1.0f/64.0f) - muA * muA;
    float muB = sB * (1.0f/64.0f), varB = qB * (1.0f/64.0f) - muB * muB;
    float rsA = rsqrtf(varA + LN_EPS), rsB = rsqrtf(varB + LN_EPS);
    float4 g0 = *(const float4*)(gamma + rowoff);
    float4 g1 = *(const float4*)(gamma + rowoff + 4);
    float4 t0 = *(const float4*)(beta + rowoff);
    float4 t1 = *(const float4*)(beta + rowoff + 4);
    float gm[8] = {g0.x,g0.y,g0.z,g0.w,g1.x,g1.y,g1.z,g1.w};
    float bt[8] = {t0.x,t0.y,t0.z,t0.w,t1.x,t1.y,t1.z,t1.w};
    if (g == 0){
      float4 o0, o1;
      o0.x=(hvA[0]-muA)*rsA*gm[0]+bt[0]; o0.y=(hvA[1]-muA)*rsA*gm[1]+bt[1];
      o0.z=(hvA[2]-muA)*rsA*gm[2]+bt[2]; o0.w=(hvA[3]-muA)*rsA*gm[3]+bt[3];
      o1.x=(hvA[4]-muA)*rsA*gm[4]+bt[4]; o1.y=(hvA[5]-muA)*rsA*gm[5]+bt[5];
      o1.z=(hvA[6]-muA)*rsA*gm[6]+bt[6]; o1.w=(hvA[7]-muA)*rsA*gm[7]+bt[7];
      *(float4*)(hn + ixA) = o0; *(float4*)(hn + ixA + 4) = o1;
    } else if (g == 1){
      float4 o0, o1;
      o0.x=(hvB[0]-muB)*rsB*gm[0]+bt[0]; o0.y=(hvB[1]-muB)*rsB*gm[1]+bt[1];
      o0.z=(hvB[2]-muB)*rsB*gm[2]+bt[2]; o0.w=(hvB[3]-muB)*rsB*gm[3]+bt[3];
      o1.x=(hvB[4]-muB)*rsB*gm[4]+bt[4]; o1.y=(hvB[5]-muB)*rsB*gm[5]+bt[5];
      o1.z=(hvB[6]-muB)*rsB*gm[6]+bt[6]; o1.w=(hvB[7]-muB)*rsB*gm[7]+bt[7];
      *(float4*)(hn + ixB) = o0; *(float4*)(hn + ixB + 4) = o1;
    }
  }
}

extern "C" void kernel_launch(void* const* d_in, const int* in_sizes, int n_in,
                              void* d_out, int out_size, void* d_ws, size_t ws_size,
                              hipStream_t stream){
  const float* x     = (const float*)d_in[0];
  const int*   ep    = (const int*)d_in[1];
  const int*   en    = (const int*)d_in[2];
  const float* tvec  = (const float*)d_in[3];
  const float* W_enc = (const float*)d_in[4];
  const float* b_enc = (const float*)d_in[5];
  const float* W_pos = (const float*)d_in[6];
  const float* b_pos = (const float*)d_in[7];
  const float* W_neg = (const float*)d_in[8];
  const float* b_neg = (const float*)d_in[9];
  const float* W_pp  = (const float*)d_in[10];
  const float* b_pp  = (const float*)d_in[11];
  const float* W_pn  = (const float*)d_in[12];
  const float* b_pn  = (const float*)d_in[13];
  const float* gamma = (const float*)d_in[14];
  const float* beta  = (const float*)d_in[15];
  float* hbase = (float*)d_out;

  char* w = (char*)d_ws;
  auto alloc = [&](size_t bytes) -> char* {
    char* p = w;
    w += (bytes + 255) & ~(size_t)255;
    return p;
  };
  uint*  bin_cur = (uint*)alloc(2 * NB2 * 4);
  int*   cnt_p = (int*)alloc(N_NODES * 4);
  int*   cnt_n = (int*)alloc(N_NODES * 4);
  int*   off_p = (int*)alloc((N_NODES + 1) * 4);
  int*   off_n = (int*)alloc((N_NODES + 1) * 4);
  float* dinv_p= (float*)alloc(N_NODES * 4);
  float* dinv_n= (float*)alloc(N_NODES * 4);
  uint*  recs_p= (uint*)alloc((size_t)NB2 * CAP2 * 4);
  uint*  recs_n= (uint*)alloc((size_t)NB2 * CAP2 * 4);
  unsigned short* cs_p = (unsigned short*)alloc((size_t)N_EDGES * 2);
  unsigned short* cs_n = (unsigned short*)alloc((size_t)N_EDGES * 2);
  unsigned short* xs_p = (unsigned short*)alloc((size_t)(N_NODES + 1) * HID * 2);
  unsigned short* xs_n = (unsigned short*)alloc((size_t)(N_NODES + 1) * HID * 2);
  float* hn    = (float*)alloc((size_t)N_NODES * HID * 4);
  float* accb  = (float*)alloc((size_t)N_NODES * HID * 4);
  float* Wc_p  = (float*)alloc(HID * HID * 4);
  float* Wc_n  = (float*)alloc(HID * HID * 4);
  float* bc    = (float*)alloc(HID * 4);

  hipMemsetAsync(bin_cur, 0, 2 * NB2 * 4, stream);

  dim3 blk(256);
  const int NBLK_A = 2 * ((N_EDGES + 8191) / 8192);
  prep_kernel<<<17, blk, 0, stream>>>(W_pp, W_pos, W_pn, W_neg, b_pos, b_pp, b_neg, b_pn,
                                      Wc_p, Wc_n, bc, xs_p, xs_n);
  binA_kernel<<<NBLK_A, blk, 0, stream>>>(ep, en, bin_cur, recs_p, recs_n);
  fillC_kernel<<<2 * NB2, blk, 0, stream>>>(bin_cur, recs_p, recs_n,
                                            cnt_p, cnt_n, dinv_p, dinv_n, cs_p, cs_n);
  scan16_kernel<<<16, 1024, 0, stream>>>(bin_cur, cnt_p, off_p, cnt_n, off_n);
  enc_kernel<<<1024, blk, 0, stream>>>(x, W_enc, b_enc, gamma, beta, hbase, hn);

  for (int s = 0; s < 8; ++s){
    conv_kernel<<<1024, blk, 0, stream>>>(hn, Wc_p, Wc_n, dinv_p, dinv_n, xs_p, xs_n);
    gatherrk_kernel<<<(N_NODES / 2 + 3) / 4, blk, 0, stream>>>(
        xs_p, xs_n, cs_p, off_p, dinv_p, cs_n, off_n, dinv_n,
        bc, gamma, beta, tvec, hbase, accb, hn, s & 3, (s < 7) ? 1 : 0);
  }
}